// Round 7
// baseline (578.194 us; speedup 1.0000x reference)
//
#include <hip/hip_runtime.h>
#include <hip/hip_bf16.h>

typedef unsigned short ushortT;
typedef unsigned int uintT;
typedef __attribute__((ext_vector_type(8))) short bf16x8;
typedef __attribute__((ext_vector_type(4))) float f32x4;
typedef __attribute__((ext_vector_type(4))) unsigned short us4;

__device__ __forceinline__ ushortT f2bf(float f) {
    union { float f; uintT u; } x; x.f = f;
    uintT r = x.u + 0x7fffu + ((x.u >> 16) & 1u);
    return (ushortT)(r >> 16);
}
__device__ __forceinline__ float bf2f(ushortT u) {
    union { uintT u; float f; } x; x.u = ((uintT)u) << 16; return x.f;
}

#define ZLD 132   // Zt row stride: 128 v-chunk + 4 pad

// ---------------------------------------------------------------------------
// K0: column-softmax of W1/W2, e = emb @ sW, row-normalize.  grid=2 (e1, e2)
// ---------------------------------------------------------------------------
__global__ __launch_bounds__(256) void k_embed(const float* __restrict__ emb,
                                               const float* __restrict__ W1,
                                               const float* __restrict__ W2,
                                               float* __restrict__ e1,
                                               float* __restrict__ e2) {
    __shared__ float sW[800];
    __shared__ float sWs[800];
    const float* W = (blockIdx.x == 0) ? W1 : W2;
    float* e = (blockIdx.x == 0) ? e1 : e2;
    int tid = threadIdx.x;
    for (int i = tid; i < 800; i += 256) sW[i] = W[i];
    __syncthreads();
    if (tid < 20) {
        float mx = -1e30f;
        for (int i = 0; i < 40; ++i) mx = fmaxf(mx, sW[i * 20 + tid]);
        float s = 0.f;
        for (int i = 0; i < 40; ++i) s += __expf(sW[i * 20 + tid] - mx);
        float inv = 1.f / s;
        for (int i = 0; i < 40; ++i) sWs[i * 20 + tid] = __expf(sW[i * 20 + tid] - mx) * inv;
    }
    __syncthreads();
    for (int row = tid; row < 512; row += 256) {
        float acc[20];
        #pragma unroll
        for (int j = 0; j < 20; ++j) acc[j] = 0.f;
        for (int i = 0; i < 40; ++i) {
            float ev = emb[row * 40 + i];
            #pragma unroll
            for (int j = 0; j < 20; ++j) acc[j] += ev * sWs[i * 20 + j];
        }
        float s = 0.f;
        #pragma unroll
        for (int j = 0; j < 20; ++j) s += acc[j] * acc[j];
        float scale = 1.f / (sqrtf(s) + 1e-8f);
        #pragma unroll
        for (int j = 0; j < 20; ++j) e[row * 20 + j] = acc[j] * scale;
    }
}

// ---------------------------------------------------------------------------
// K1: A[v][w] = adj>0 ? e1[v].e2[w] + adj : 9e-15 ; d[v] = 1/sqrt(rowsum)
// ---------------------------------------------------------------------------
__global__ __launch_bounds__(256) void k_adj(const float* __restrict__ adj,
                                             const float* __restrict__ e1,
                                             const float* __restrict__ e2,
                                             float* __restrict__ A,
                                             float* __restrict__ d) {
    int v = blockIdx.x, tid = threadIdx.x;
    __shared__ float ev[20];
    if (tid < 20) ev[tid] = e1[v * 20 + tid];
    __syncthreads();
    float local = 0.f;
    for (int w = tid; w < 512; w += 256) {
        float dot = 0.f;
        #pragma unroll
        for (int j = 0; j < 20; ++j) dot += ev[j] * e2[w * 20 + j];
        float av = adj[v * 512 + w];
        float Av = (av > 0.f) ? (dot + av) : 9e-15f;
        A[v * 512 + w] = Av;
        local += Av;
    }
    __shared__ float red[256];
    red[tid] = local;
    __syncthreads();
    for (int s = 128; s > 0; s >>= 1) {
        if (tid < s) red[tid] += red[tid + s];
        __syncthreads();
    }
    if (tid == 0) d[v] = 1.f / sqrtf(red[0]);
}

// ---------------------------------------------------------------------------
// K2: P slot0 = I ; slot1 = M[w][v] = Ls^T = -d[v]*d[w]*A[v][w]  (bf16)
// ---------------------------------------------------------------------------
__global__ __launch_bounds__(256) void k_m(const float* __restrict__ A,
                                           const float* __restrict__ d,
                                           ushortT* __restrict__ P) {
    int w = blockIdx.x, tid = threadIdx.x;
    float dw = d[w];
    for (int v = tid; v < 512; v += 256) {
        float val = -d[v] * dw * A[v * 512 + w];
        P[512 * 512 + w * 512 + v] = f2bf(val);
        P[w * 512 + v] = (v == w) ? (ushortT)0x3F80 : (ushortT)0;
    }
}

// ---------------------------------------------------------------------------
// K3: merged prep. Blocks 0..159: Wq build. Blocks 160+: x -> xbf convert.
// ---------------------------------------------------------------------------
__global__ __launch_bounds__(256) void k_prep(const float* __restrict__ x,
                                              ushortT* __restrict__ xbf,
                                              const float* __restrict__ mlp_w,
                                              ushortT* __restrict__ Wq) {
    int bx = blockIdx.x;
    if (bx < 160) {
        int idx = bx * 256 + threadIdx.x;
        if (idx >= 10 * 64 * 64) return;
        int q = idx >> 12, rem = idx & 4095, o = rem >> 6, c = rem & 63;
        float v;
        if (q == 0) {
            v = 0.f;
            #pragma unroll
            for (int k = 0; k < 4; ++k) v += mlp_w[o * 832 + k * 64 + c];
        } else {
            v = mlp_w[o * 832 + (q + 3) * 64 + c];
        }
        Wq[idx] = f2bf(v);
    } else {
        size_t i = (size_t)(bx - 160) * 256 + threadIdx.x;
        int c = (int)(i & 15) * 4;
        int v = (int)((i >> 4) & 511);
        int bt = (int)(i >> 13);            // b*12 + t
        int b = bt / 12, t = bt - b * 12;
        f32x4 f = *(const f32x4*)(x + (((size_t)b * 512 + v) * 12 + t) * 64 + c);
        us4 o = { f2bf(f[0]), f2bf(f[1]), f2bf(f[2]), f2bf(f[3]) };
        *(us4*)(xbf + ((size_t)bt * 512 + v) * 64 + c) = o;
    }
}

// ---------------------------------------------------------------------------
// 512x512x512 bf16 MFMA GEMM (+Chebyshev epilogue). Supports a second
// independent GEMM in blocks 64..127 (A2/B2/out3, mode 0).
// ---------------------------------------------------------------------------
__global__ __launch_bounds__(256) void k_gemm512(const ushortT* __restrict__ A,
                                                 const ushortT* __restrict__ B,
                                                 ushortT* __restrict__ out1,
                                                 ushortT* __restrict__ out2,
                                                 int mode,
                                                 const ushortT* __restrict__ aux,
                                                 const ushortT* __restrict__ A2,
                                                 const ushortT* __restrict__ B2,
                                                 ushortT* __restrict__ out3) {
    int bx = blockIdx.x;
    if (bx >= 64) { A = A2; B = B2; out1 = out3; out2 = nullptr; mode = 0; bx -= 64; }
    int wave = threadIdx.x >> 6, lane = threadIdx.x & 63;
    int lr = lane & 15, lg = lane >> 4;
    int mbase = (bx >> 3) * 64;
    int nbase = (bx & 7) * 64 + wave * 16;
    f32x4 acc[4] = {};
    for (int kk = 0; kk < 16; ++kk) {
        int k0 = kk * 32 + lg * 8;
        bf16x8 bfr;
        #pragma unroll
        for (int j = 0; j < 8; ++j) bfr[j] = (short)B[(k0 + j) * 512 + nbase + lr];
        #pragma unroll
        for (int wt = 0; wt < 4; ++wt) {
            bf16x8 af = *(const bf16x8*)(A + (mbase + wt * 16 + lr) * 512 + k0);
            acc[wt] = __builtin_amdgcn_mfma_f32_16x16x32_bf16(af, bfr, acc[wt], 0, 0, 0);
        }
    }
    #pragma unroll
    for (int wt = 0; wt < 4; ++wt)
        #pragma unroll
        for (int r = 0; r < 4; ++r) {
            int row = mbase + wt * 16 + lg * 4 + r;
            int col = nbase + lr;
            float v = acc[wt][r];
            out1[row * 512 + col] = f2bf(v);
            if (mode == 1) out2[row * 512 + col] = f2bf(2.f * v - (row == col ? 1.f : 0.f));
            else if (mode == 2) out2[row * 512 + col] = f2bf(4.f * v - 3.f * bf2f(aux[row * 512 + col]));
        }
}

// ---------------------------------------------------------------------------
// Main fused kernel v7:  out = relu(x + bias + sum_q P_q @ (X @ Wq^T))
//   Uniform 40-phase pipeline (10 q x 4 128-v chunks, identity = real GEMM
//   vs P_0=I). Double-buffered Zt (2x64x132, 33.8KB), one barrier per phase.
//   Rolling 8-frag P register ring refilled per-kk from item p+1 (full-phase
//   load coverage). X loads for item p+1 issued at phase top. ~112 VGPR.
// ---------------------------------------------------------------------------
template<bool XBF>
__global__ __launch_bounds__(512, 2) void k_main(const float* __restrict__ x,
                                                 const ushortT* __restrict__ xbf,
                                                 const ushortT* __restrict__ P,
                                                 const ushortT* __restrict__ Wq,
                                                 const float* __restrict__ bias,
                                                 float* __restrict__ out) {
    __shared__ ushortT Zt[2][64 * ZLD];
    const int SZ = 512 * 512;
    int bid = blockIdx.x;
    int b = bid / 24, rr = bid % 24, tt = rr >> 1, half = rr & 1;
    int tid = threadIdx.x, wave = tid >> 6, lane = tid & 63;
    int lr = lane & 15, lg = lane >> 4;
    int wbase = half * 256 + wave * 32;   // wave's 32 output rows

    const ushortT* xq = xbf + (size_t)(b * 12 + tt) * 512 * 64;
    const float*   xqf = x + ((size_t)b * 512 * 12 + tt) * 64;

    f32x4 oacc[2][4] = {};
    bf16x8 aP[8];

    // P fragment base for work item it = (q = it>>2, ch = it&3)
    auto pbase = [&](int it) -> const ushortT* {
        return P + (size_t)(it >> 2) * SZ + (it & 3) * 128
                 + (size_t)(wbase + lr) * 512 + lg * 8;
    };

    // load X fragments for item it (wave covers v-rows ch*128+wave*16 ..+16)
    auto xload = [&](int it, bf16x8& xf0, bf16x8& xf1) {
        int vrow = (it & 3) * 128 + wave * 16 + lr;
        if (XBF) {
            xf0 = *(const bf16x8*)(xq + vrow * 64 + lg * 8);
            xf1 = *(const bf16x8*)(xq + vrow * 64 + 32 + lg * 8);
        } else {
            const float* px = xqf + (size_t)vrow * 768 + lg * 8;
            f32x4 f0 = *(const f32x4*)px;
            f32x4 f1 = *(const f32x4*)(px + 4);
            f32x4 f2 = *(const f32x4*)(px + 32);
            f32x4 f3 = *(const f32x4*)(px + 36);
            bf16x8 v0, v1;
            v0[0] = (short)f2bf(f0[0]); v0[1] = (short)f2bf(f0[1]);
            v0[2] = (short)f2bf(f0[2]); v0[3] = (short)f2bf(f0[3]);
            v0[4] = (short)f2bf(f1[0]); v0[5] = (short)f2bf(f1[1]);
            v0[6] = (short)f2bf(f1[2]); v0[7] = (short)f2bf(f1[3]);
            v1[0] = (short)f2bf(f2[0]); v1[1] = (short)f2bf(f2[1]);
            v1[2] = (short)f2bf(f2[2]); v1[3] = (short)f2bf(f2[3]);
            v1[4] = (short)f2bf(f3[0]); v1[5] = (short)f2bf(f3[1]);
            v1[6] = (short)f2bf(f3[2]); v1[7] = (short)f2bf(f3[3]);
            xf0 = v0; xf1 = v1;
        }
    };

    // z-compute item it into Zt[pbuf] from preloaded xf0/xf1
    auto zcompute = [&](int it, int pbuf, bf16x8 xf0, bf16x8 xf1) {
        const ushortT* wqp = Wq + (it >> 2) * 4096;
        #pragma unroll
        for (int ot = 0; ot < 4; ++ot) {
            int o = ot * 16 + lr;
            bf16x8 wf0 = *(const bf16x8*)(wqp + o * 64 + lg * 8);
            bf16x8 wf1 = *(const bf16x8*)(wqp + o * 64 + 32 + lg * 8);
            f32x4 z = {};
            z = __builtin_amdgcn_mfma_f32_16x16x32_bf16(xf0, wf0, z, 0, 0, 0);
            z = __builtin_amdgcn_mfma_f32_16x16x32_bf16(xf1, wf1, z, 0, 0, 0);
            us4 pk = { f2bf(z[0]), f2bf(z[1]), f2bf(z[2]), f2bf(z[3]) };
            *(us4*)&Zt[pbuf][o * ZLD + wave * 16 + lg * 4] = pk;
        }
    };

    // GEMM over one chunk: consume Zt[cbuf] + aP ring, refill ring from pn
    auto gemmphase = [&](int cbuf, const ushortT* pnb) {
        #pragma unroll
        for (int kk = 0; kk < 4; ++kk) {
            int vb = kk * 32 + lg * 8;
            bf16x8 b0 = *(const bf16x8*)&Zt[cbuf][(0 * 16 + lr) * ZLD + vb];
            bf16x8 b1 = *(const bf16x8*)&Zt[cbuf][(1 * 16 + lr) * ZLD + vb];
            bf16x8 b2 = *(const bf16x8*)&Zt[cbuf][(2 * 16 + lr) * ZLD + vb];
            bf16x8 b3 = *(const bf16x8*)&Zt[cbuf][(3 * 16 + lr) * ZLD + vb];
            oacc[0][0] = __builtin_amdgcn_mfma_f32_16x16x32_bf16(aP[kk*2+0], b0, oacc[0][0], 0, 0, 0);
            oacc[1][0] = __builtin_amdgcn_mfma_f32_16x16x32_bf16(aP[kk*2+1], b0, oacc[1][0], 0, 0, 0);
            oacc[0][1] = __builtin_amdgcn_mfma_f32_16x16x32_bf16(aP[kk*2+0], b1, oacc[0][1], 0, 0, 0);
            oacc[1][1] = __builtin_amdgcn_mfma_f32_16x16x32_bf16(aP[kk*2+1], b1, oacc[1][1], 0, 0, 0);
            oacc[0][2] = __builtin_amdgcn_mfma_f32_16x16x32_bf16(aP[kk*2+0], b2, oacc[0][2], 0, 0, 0);
            oacc[1][2] = __builtin_amdgcn_mfma_f32_16x16x32_bf16(aP[kk*2+1], b2, oacc[1][2], 0, 0, 0);
            oacc[0][3] = __builtin_amdgcn_mfma_f32_16x16x32_bf16(aP[kk*2+0], b3, oacc[0][3], 0, 0, 0);
            oacc[1][3] = __builtin_amdgcn_mfma_f32_16x16x32_bf16(aP[kk*2+1], b3, oacc[1][3], 0, 0, 0);
            // refill consumed slots from next item (WAR keeps ordering)
            aP[kk*2+0] = *(const bf16x8*)(pnb + kk * 32);
            aP[kk*2+1] = *(const bf16x8*)(pnb + 16 * 512 + kk * 32);
        }
    };

    // ---- prologue: produce item 0, prefill ring for item 0 ----
    {
        const ushortT* p0 = pbase(0);
        #pragma unroll
        for (int kk = 0; kk < 4; ++kk) {
            aP[kk*2+0] = *(const bf16x8*)(p0 + kk * 32);
            aP[kk*2+1] = *(const bf16x8*)(p0 + 16 * 512 + kk * 32);
        }
        bf16x8 xf0, xf1;
        xload(0, xf0, xf1);
        zcompute(0, 0, xf0, xf1);
    }
    __syncthreads();

    // ---- 40 phases, one barrier each ----
    #pragma unroll 1
    for (int p2 = 0; p2 < 20; ++p2) {
        {   // even phase p: consume buf0, produce item p+1 -> buf1
            int p = p2 * 2;
            int pn = (p < 39) ? p + 1 : 39;
            bf16x8 xf0, xf1;
            xload(pn, xf0, xf1);                 // issue X loads early
            gemmphase(0, pbase(pn));
            if (p < 39) zcompute(pn, 1, xf0, xf1);
            __syncthreads();
        }
        {   // odd phase p: consume buf1, produce item p+1 -> buf0
            int p = p2 * 2 + 1;
            int pn = (p < 39) ? p + 1 : 39;
            bf16x8 xf0, xf1;
            xload(pn, xf0, xf1);
            gemmphase(1, pbase(pn));
            if (p < 39) zcompute(pn, 0, xf0, xf1);
            __syncthreads();
        }
    }

    // ---- epilogue: residual + bias + relu, fp32 out ----
    #pragma unroll
    for (int wt = 0; wt < 2; ++wt)
        #pragma unroll
        for (int ot = 0; ot < 4; ++ot)
            #pragma unroll
            for (int r = 0; r < 4; ++r) {
                int w = wbase + wt * 16 + lg * 4 + r;
                int o = ot * 16 + lr;
                size_t oi = (((size_t)b * 512 + w) * 12 + tt) * 64 + o;
                float v = oacc[wt][ot][r] + x[oi] + bias[o];
                out[oi] = (v > 0.f) ? v : 0.f;
            }
}

// ---------------------------------------------------------------------------
extern "C" void kernel_launch(void* const* d_in, const int* in_sizes, int n_in,
                              void* d_out, int out_size, void* d_ws, size_t ws_size,
                              hipStream_t stream) {
    const float* x    = (const float*)d_in[0];
    const float* adj  = (const float*)d_in[1];
    const float* emb  = (const float*)d_in[2];
    const float* W1   = (const float*)d_in[3];
    const float* W2   = (const float*)d_in[4];
    const float* mlpw = (const float*)d_in[5];
    const float* mlpb = (const float*)d_in[6];
    float* out = (float*)d_out;

    char* ws = (char*)d_ws;
    float*   e1   = (float*)(ws + 0);
    float*   e2   = (float*)(ws + 65536);
    float*   A    = (float*)(ws + 131072);
    float*   dvec = (float*)(ws + 1179648);
    ushortT* P    = (ushortT*)(ws + 1183744);            // [10][512][512] bf16
    ushortT* Wq   = (ushortT*)(ws + 6426624);            // [10][64][64]  bf16
    ushortT* xbf  = (ushortT*)(ws + 6508544);            // [b][t][512][64] bf16 = 24MB
    const size_t WS_NEED = 6508544 + (size_t)32 * 12 * 512 * 64 * 2;
    const bool use_xbf = (ws_size >= WS_NEED);

    k_embed<<<2, 256, 0, stream>>>(emb, W1, W2, e1, e2);
    k_adj<<<512, 256, 0, stream>>>(adj, e1, e2, A, dvec);
    k_m<<<512, 256, 0, stream>>>(A, dvec, P);
    k_prep<<<use_xbf ? 12448 : 160, 256, 0, stream>>>(x, xbf, mlpw, Wq);

    const int SZ = 512 * 512;
    ushortT *S1 = P + 1 * SZ, *S2 = P + 2 * SZ, *S3 = P + 3 * SZ, *S4 = P + 4 * SZ,
            *S5 = P + 5 * SZ, *S6 = P + 6 * SZ, *S7 = P + 7 * SZ, *S8 = P + 8 * SZ,
            *S9 = P + 9 * SZ;
    // S2 = M^2 ; S4 = 2M^2 - I (T2^T)
    k_gemm512<<<64, 256, 0, stream>>>(S1, S1, S2, S4, 1, nullptr, nullptr, nullptr, nullptr);
    // S3 = M^3 ; S7 = 4M^3 - 3M (T3^T)  ||  S5 = (T2^T)^2
    k_gemm512<<<128, 256, 0, stream>>>(S1, S2, S3, S7, 2, S1, S4, S4, S5);
    // S6 = (T2^T)^3  ||  S8 = (T3^T)^2
    k_gemm512<<<128, 256, 0, stream>>>(S4, S5, S6, nullptr, 0, nullptr, S7, S7, S8);
    // S9 = (T3^T)^3
    k_gemm512<<<64, 256, 0, stream>>>(S7, S8, S9, nullptr, 0, nullptr, nullptr, nullptr, nullptr);

    if (use_xbf)
        k_main<true><<<768, 512, 0, stream>>>(x, xbf, P, Wq, mlpb, out);
    else
        k_main<false><<<768, 512, 0, stream>>>(x, nullptr, P, Wq, mlpb, out);
    (void)in_sizes; (void)n_in; (void)out_size;
}

// Round 8
// 534.060 us; speedup vs baseline: 1.0826x; 1.0826x over previous
//
#include <hip/hip_runtime.h>
#include <hip/hip_bf16.h>

typedef unsigned short ushortT;
typedef unsigned int uintT;
typedef __attribute__((ext_vector_type(8))) short bf16x8;
typedef __attribute__((ext_vector_type(4))) float f32x4;
typedef __attribute__((ext_vector_type(4))) unsigned short us4;

__device__ __forceinline__ ushortT f2bf(float f) {
    union { float f; uintT u; } x; x.f = f;
    uintT r = x.u + 0x7fffu + ((x.u >> 16) & 1u);
    return (ushortT)(r >> 16);
}
__device__ __forceinline__ float bf2f(ushortT u) {
    union { uintT u; float f; } x; x.u = ((uintT)u) << 16; return x.f;
}

#define ZLD 260   // Zt row stride: 256 v-chunk + 4 pad (R7-verified 0-conflict shape)
#define ZSZ (64 * ZLD)

// ---------------------------------------------------------------------------
// K0: column-softmax of W1/W2, e = emb @ sW, row-normalize.  grid=2 (e1, e2)
// ---------------------------------------------------------------------------
__global__ __launch_bounds__(256) void k_embed(const float* __restrict__ emb,
                                               const float* __restrict__ W1,
                                               const float* __restrict__ W2,
                                               float* __restrict__ e1,
                                               float* __restrict__ e2) {
    __shared__ float sW[800];
    __shared__ float sWs[800];
    const float* W = (blockIdx.x == 0) ? W1 : W2;
    float* e = (blockIdx.x == 0) ? e1 : e2;
    int tid = threadIdx.x;
    for (int i = tid; i < 800; i += 256) sW[i] = W[i];
    __syncthreads();
    if (tid < 20) {
        float mx = -1e30f;
        for (int i = 0; i < 40; ++i) mx = fmaxf(mx, sW[i * 20 + tid]);
        float s = 0.f;
        for (int i = 0; i < 40; ++i) s += __expf(sW[i * 20 + tid] - mx);
        float inv = 1.f / s;
        for (int i = 0; i < 40; ++i) sWs[i * 20 + tid] = __expf(sW[i * 20 + tid] - mx) * inv;
    }
    __syncthreads();
    for (int row = tid; row < 512; row += 256) {
        float acc[20];
        #pragma unroll
        for (int j = 0; j < 20; ++j) acc[j] = 0.f;
        for (int i = 0; i < 40; ++i) {
            float ev = emb[row * 40 + i];
            #pragma unroll
            for (int j = 0; j < 20; ++j) acc[j] += ev * sWs[i * 20 + j];
        }
        float s = 0.f;
        #pragma unroll
        for (int j = 0; j < 20; ++j) s += acc[j] * acc[j];
        float scale = 1.f / (sqrtf(s) + 1e-8f);
        #pragma unroll
        for (int j = 0; j < 20; ++j) e[row * 20 + j] = acc[j] * scale;
    }
}

// ---------------------------------------------------------------------------
// K1: A[v][w] = adj>0 ? e1[v].e2[w] + adj : 9e-15 ; d[v] = 1/sqrt(rowsum)
// ---------------------------------------------------------------------------
__global__ __launch_bounds__(256) void k_adj(const float* __restrict__ adj,
                                             const float* __restrict__ e1,
                                             const float* __restrict__ e2,
                                             float* __restrict__ A,
                                             float* __restrict__ d) {
    int v = blockIdx.x, tid = threadIdx.x;
    __shared__ float ev[20];
    if (tid < 20) ev[tid] = e1[v * 20 + tid];
    __syncthreads();
    float local = 0.f;
    for (int w = tid; w < 512; w += 256) {
        float dot = 0.f;
        #pragma unroll
        for (int j = 0; j < 20; ++j) dot += ev[j] * e2[w * 20 + j];
        float av = adj[v * 512 + w];
        float Av = (av > 0.f) ? (dot + av) : 9e-15f;
        A[v * 512 + w] = Av;
        local += Av;
    }
    __shared__ float red[256];
    red[tid] = local;
    __syncthreads();
    for (int s = 128; s > 0; s >>= 1) {
        if (tid < s) red[tid] += red[tid + s];
        __syncthreads();
    }
    if (tid == 0) d[v] = 1.f / sqrtf(red[0]);
}

// ---------------------------------------------------------------------------
// K2: P slot1 = M[w][v] = Ls^T = -d[v]*d[w]*A[v][w]  (bf16)
// ---------------------------------------------------------------------------
__global__ __launch_bounds__(256) void k_m(const float* __restrict__ A,
                                           const float* __restrict__ d,
                                           ushortT* __restrict__ P) {
    int w = blockIdx.x, tid = threadIdx.x;
    float dw = d[w];
    for (int v = tid; v < 512; v += 256) {
        float val = -d[v] * dw * A[v * 512 + w];
        P[512 * 512 + w * 512 + v] = f2bf(val);
    }
}

// ---------------------------------------------------------------------------
// K3: merged prep. Blocks 0..159: Wq build. Blocks 160+: x -> xbf convert.
// ---------------------------------------------------------------------------
__global__ __launch_bounds__(256) void k_prep(const float* __restrict__ x,
                                              ushortT* __restrict__ xbf,
                                              const float* __restrict__ mlp_w,
                                              ushortT* __restrict__ Wq) {
    int bx = blockIdx.x;
    if (bx < 160) {
        int idx = bx * 256 + threadIdx.x;
        if (idx >= 10 * 64 * 64) return;
        int q = idx >> 12, rem = idx & 4095, o = rem >> 6, c = rem & 63;
        float v;
        if (q == 0) {
            v = 0.f;
            #pragma unroll
            for (int k = 0; k < 4; ++k) v += mlp_w[o * 832 + k * 64 + c];
        } else {
            v = mlp_w[o * 832 + (q + 3) * 64 + c];
        }
        Wq[idx] = f2bf(v);
    } else {
        size_t i = (size_t)(bx - 160) * 256 + threadIdx.x;
        int c = (int)(i & 15) * 4;
        int v = (int)((i >> 4) & 511);
        int bt = (int)(i >> 13);            // b*12 + t
        int b = bt / 12, t = bt - b * 12;
        f32x4 f = *(const f32x4*)(x + (((size_t)b * 512 + v) * 12 + t) * 64 + c);
        us4 o = { f2bf(f[0]), f2bf(f[1]), f2bf(f[2]), f2bf(f[3]) };
        *(us4*)(xbf + ((size_t)bt * 512 + v) * 64 + c) = o;
    }
}

// ---------------------------------------------------------------------------
// 512x512x512 bf16 MFMA GEMM (+Chebyshev epilogue). Supports a second
// independent GEMM in blocks 64..127 (A2/B2/out3, mode 0).
// ---------------------------------------------------------------------------
__global__ __launch_bounds__(256) void k_gemm512(const ushortT* __restrict__ A,
                                                 const ushortT* __restrict__ B,
                                                 ushortT* __restrict__ out1,
                                                 ushortT* __restrict__ out2,
                                                 int mode,
                                                 const ushortT* __restrict__ aux,
                                                 const ushortT* __restrict__ A2,
                                                 const ushortT* __restrict__ B2,
                                                 ushortT* __restrict__ out3) {
    int bx = blockIdx.x;
    if (bx >= 64) { A = A2; B = B2; out1 = out3; out2 = nullptr; mode = 0; bx -= 64; }
    int wave = threadIdx.x >> 6, lane = threadIdx.x & 63;
    int lr = lane & 15, lg = lane >> 4;
    int mbase = (bx >> 3) * 64;
    int nbase = (bx & 7) * 64 + wave * 16;
    f32x4 acc[4] = {};
    for (int kk = 0; kk < 16; ++kk) {
        int k0 = kk * 32 + lg * 8;
        bf16x8 bfr;
        #pragma unroll
        for (int j = 0; j < 8; ++j) bfr[j] = (short)B[(k0 + j) * 512 + nbase + lr];
        #pragma unroll
        for (int wt = 0; wt < 4; ++wt) {
            bf16x8 af = *(const bf16x8*)(A + (mbase + wt * 16 + lr) * 512 + k0);
            acc[wt] = __builtin_amdgcn_mfma_f32_16x16x32_bf16(af, bfr, acc[wt], 0, 0, 0);
        }
    }
    #pragma unroll
    for (int wt = 0; wt < 4; ++wt)
        #pragma unroll
        for (int r = 0; r < 4; ++r) {
            int row = mbase + wt * 16 + lg * 4 + r;
            int col = nbase + lr;
            float v = acc[wt][r];
            out1[row * 512 + col] = f2bf(v);
            if (mode == 1) out2[row * 512 + col] = f2bf(2.f * v - (row == col ? 1.f : 0.f));
            else if (mode == 2) out2[row * 512 + col] = f2bf(4.f * v - 3.f * bf2f(aux[row * 512 + col]));
        }
}

// ---------------------------------------------------------------------------
// Main fused kernel v8:  out = relu(x + bias + sum_q P_q @ (X @ Wq^T))
//   R5 skeleton + double-buffered 256-v chunked Zt (one zero-wait barrier
//   per item; producer ran one item earlier) + R7's 0-conflict layout.
//   Items: (q,ch) for q=1..9, ch=0,1 (18 items). q0 = direct Zt->oacc read.
// ---------------------------------------------------------------------------
template<bool XBF>
__global__ __launch_bounds__(512, 2) void k_main(const float* __restrict__ x,
                                                 const ushortT* __restrict__ xbf,
                                                 const ushortT* __restrict__ P,
                                                 const ushortT* __restrict__ Wq,
                                                 const float* __restrict__ bias,
                                                 float* __restrict__ out) {
    __shared__ ushortT Zt[2 * ZSZ];
    const int SZ = 512 * 512;
    int bid = blockIdx.x;
    int b = bid / 24, rr = bid % 24, tt = rr >> 1, half = rr & 1;
    int tid = threadIdx.x, wave = tid >> 6, lane = tid & 63;
    int lr = lane & 15, lg = lane >> 4;
    int wbase = half * 256 + wave * 32;   // wave's 32 output rows
    int vloc = wave * 32;                 // wave's producer v-rows within chunk

    const ushortT* xq = xbf + (size_t)(b * 12 + tt) * 512 * 64;
    const float*   xqf = x + ((size_t)b * 512 * 12 + tt) * 64;

    f32x4 oacc[2][4] = {};

    // ---- load X fragments for chunk ch (wave's 32 v-rows) ----
    auto xload = [&](int ch, bf16x8 xf[4]) {
        #pragma unroll
        for (int vt = 0; vt < 2; ++vt) {
            int vrow = ch * 256 + vloc + vt * 16 + lr;
            if (XBF) {
                xf[vt * 2 + 0] = *(const bf16x8*)(xq + vrow * 64 + lg * 8);
                xf[vt * 2 + 1] = *(const bf16x8*)(xq + vrow * 64 + 32 + lg * 8);
            } else {
                const float* px = xqf + (size_t)vrow * 768 + lg * 8;
                f32x4 f0 = *(const f32x4*)px;
                f32x4 f1 = *(const f32x4*)(px + 4);
                f32x4 f2 = *(const f32x4*)(px + 32);
                f32x4 f3 = *(const f32x4*)(px + 36);
                bf16x8 v0, v1;
                v0[0] = (short)f2bf(f0[0]); v0[1] = (short)f2bf(f0[1]);
                v0[2] = (short)f2bf(f0[2]); v0[3] = (short)f2bf(f0[3]);
                v0[4] = (short)f2bf(f1[0]); v0[5] = (short)f2bf(f1[1]);
                v0[6] = (short)f2bf(f1[2]); v0[7] = (short)f2bf(f1[3]);
                v1[0] = (short)f2bf(f2[0]); v1[1] = (short)f2bf(f2[1]);
                v1[2] = (short)f2bf(f2[2]); v1[3] = (short)f2bf(f2[3]);
                v1[4] = (short)f2bf(f3[0]); v1[5] = (short)f2bf(f3[1]);
                v1[6] = (short)f2bf(f3[2]); v1[7] = (short)f2bf(f3[3]);
                xf[vt * 2 + 0] = v0;
                xf[vt * 2 + 1] = v1;
            }
        }
    };

    // ---- z-compute: Zt[buf] chunk rows vloc..vloc+32 = (X @ Wq^T)^T ----
    auto zcompute = [&](int q, int buf, const bf16x8 xf[4]) {
        const ushortT* wqp = Wq + q * 4096;
        ushortT* zb = &Zt[buf * ZSZ];
        #pragma unroll
        for (int ot = 0; ot < 4; ++ot) {
            int o = ot * 16 + lr;
            bf16x8 wf0 = *(const bf16x8*)(wqp + o * 64 + lg * 8);
            bf16x8 wf1 = *(const bf16x8*)(wqp + o * 64 + 32 + lg * 8);
            f32x4 z0 = {}, z1 = {};
            z0 = __builtin_amdgcn_mfma_f32_16x16x32_bf16(xf[0], wf0, z0, 0, 0, 0);
            z0 = __builtin_amdgcn_mfma_f32_16x16x32_bf16(xf[1], wf1, z0, 0, 0, 0);
            z1 = __builtin_amdgcn_mfma_f32_16x16x32_bf16(xf[2], wf0, z1, 0, 0, 0);
            z1 = __builtin_amdgcn_mfma_f32_16x16x32_bf16(xf[3], wf1, z1, 0, 0, 0);
            int base = o * ZLD + vloc + lg * 4;
            us4 p0 = { f2bf(z0[0]), f2bf(z0[1]), f2bf(z0[2]), f2bf(z0[3]) };
            *(us4*)&Zt[buf * ZSZ + base] = p0;
            us4 p1 = { f2bf(z1[0]), f2bf(z1[1]), f2bf(z1[2]), f2bf(z1[3]) };
            *(us4*)&Zt[buf * ZSZ + base + 16] = p1;
            (void)zb;
        }
    };

    // ---- prologue: produce (q0, chunk=half) into buf0 ----
    {
        bf16x8 xf[4];
        xload(half, xf);
        zcompute(0, 0, xf);
    }
    __syncthreads();
    // oacc = Z_0 rows for our w; produce (q1, ch0) into buf1
    #pragma unroll
    for (int wt = 0; wt < 2; ++wt)
        #pragma unroll
        for (int ot = 0; ot < 4; ++ot) {
            int o = ot * 16 + lr;
            us4 z4 = *(const us4*)&Zt[o * ZLD + vloc + wt * 16 + lg * 4];
            oacc[wt][ot][0] = bf2f(z4[0]);
            oacc[wt][ot][1] = bf2f(z4[1]);
            oacc[wt][ot][2] = bf2f(z4[2]);
            oacc[wt][ot][3] = bf2f(z4[3]);
        }
    {
        bf16x8 xf[4];
        xload(0, xf);
        zcompute(1, 1, xf);
    }
    __syncthreads();

    // ---- 18 items: j -> (q = 1 + (j>>1), ch = j&1), consume buf[(j+1)&1],
    //      produce item j+1 into buf[j&1]. One barrier per item. ----
    #pragma unroll 2
    for (int j = 0; j < 18; ++j) {
        int q = 1 + (j >> 1), ch = j & 1;
        const int cbuf = (j + 1) & 1, pbuf = j & 1;
        bool hasNext = (j < 17);
        int qn = 1 + ((j + 1) >> 1), chn = (j + 1) & 1;

        bf16x8 xf[4];
        if (hasNext) xload(chn, xf);     // issue next item's X loads early

        const ushortT* pq = P + (size_t)q * SZ + (size_t)(wbase + lr) * 512
                              + ch * 256 + lg * 8;
        const ushortT* zc = &Zt[cbuf * ZSZ];
        #pragma unroll
        for (int kk = 0; kk < 8; ++kk) {
            bf16x8 a0 = *(const bf16x8*)(pq + kk * 32);
            bf16x8 a1 = *(const bf16x8*)(pq + 16 * 512 + kk * 32);
            int vb = kk * 32 + lg * 8;
            bf16x8 b0 = *(const bf16x8*)&zc[(0 * 16 + lr) * ZLD + vb];
            bf16x8 b1 = *(const bf16x8*)&zc[(1 * 16 + lr) * ZLD + vb];
            bf16x8 b2 = *(const bf16x8*)&zc[(2 * 16 + lr) * ZLD + vb];
            bf16x8 b3 = *(const bf16x8*)&zc[(3 * 16 + lr) * ZLD + vb];
            oacc[0][0] = __builtin_amdgcn_mfma_f32_16x16x32_bf16(a0, b0, oacc[0][0], 0, 0, 0);
            oacc[1][0] = __builtin_amdgcn_mfma_f32_16x16x32_bf16(a1, b0, oacc[1][0], 0, 0, 0);
            oacc[0][1] = __builtin_amdgcn_mfma_f32_16x16x32_bf16(a0, b1, oacc[0][1], 0, 0, 0);
            oacc[1][1] = __builtin_amdgcn_mfma_f32_16x16x32_bf16(a1, b1, oacc[1][1], 0, 0, 0);
            oacc[0][2] = __builtin_amdgcn_mfma_f32_16x16x32_bf16(a0, b2, oacc[0][2], 0, 0, 0);
            oacc[1][2] = __builtin_amdgcn_mfma_f32_16x16x32_bf16(a1, b2, oacc[1][2], 0, 0, 0);
            oacc[0][3] = __builtin_amdgcn_mfma_f32_16x16x32_bf16(a0, b3, oacc[0][3], 0, 0, 0);
            oacc[1][3] = __builtin_amdgcn_mfma_f32_16x16x32_bf16(a1, b3, oacc[1][3], 0, 0, 0);
        }

        if (hasNext) zcompute(qn, pbuf, xf);
        __syncthreads();
    }

    // ---- epilogue: residual + bias + relu, fp32 out ----
    #pragma unroll
    for (int wt = 0; wt < 2; ++wt)
        #pragma unroll
        for (int ot = 0; ot < 4; ++ot)
            #pragma unroll
            for (int r = 0; r < 4; ++r) {
                int w = wbase + wt * 16 + lg * 4 + r;
                int o = ot * 16 + lr;
                size_t oi = (((size_t)b * 512 + w) * 12 + tt) * 64 + o;
                float v = oacc[wt][ot][r] + x[oi] + bias[o];
                out[oi] = (v > 0.f) ? v : 0.f;
            }
}

// ---------------------------------------------------------------------------
extern "C" void kernel_launch(void* const* d_in, const int* in_sizes, int n_in,
                              void* d_out, int out_size, void* d_ws, size_t ws_size,
                              hipStream_t stream) {
    const float* x    = (const float*)d_in[0];
    const float* adj  = (const float*)d_in[1];
    const float* emb  = (const float*)d_in[2];
    const float* W1   = (const float*)d_in[3];
    const float* W2   = (const float*)d_in[4];
    const float* mlpw = (const float*)d_in[5];
    const float* mlpb = (const float*)d_in[6];
    float* out = (float*)d_out;

    char* ws = (char*)d_ws;
    float*   e1   = (float*)(ws + 0);
    float*   e2   = (float*)(ws + 65536);
    float*   A    = (float*)(ws + 131072);
    float*   dvec = (float*)(ws + 1179648);
    ushortT* P    = (ushortT*)(ws + 1183744);            // [10][512][512] bf16 (slot0 unused)
    ushortT* Wq   = (ushortT*)(ws + 6426624);            // [10][64][64]  bf16
    ushortT* xbf  = (ushortT*)(ws + 6508544);            // [b][t][512][64] bf16 = 24MB
    const size_t WS_NEED = 6508544 + (size_t)32 * 12 * 512 * 64 * 2;
    const bool use_xbf = (ws_size >= WS_NEED);

    k_embed<<<2, 256, 0, stream>>>(emb, W1, W2, e1, e2);
    k_adj<<<512, 256, 0, stream>>>(adj, e1, e2, A, dvec);
    k_m<<<512, 256, 0, stream>>>(A, dvec, P);
    k_prep<<<use_xbf ? 12448 : 160, 256, 0, stream>>>(x, xbf, mlpw, Wq);

    const int SZ = 512 * 512;
    ushortT *S1 = P + 1 * SZ, *S2 = P + 2 * SZ, *S3 = P + 3 * SZ, *S4 = P + 4 * SZ,
            *S5 = P + 5 * SZ, *S6 = P + 6 * SZ, *S7 = P + 7 * SZ, *S8 = P + 8 * SZ,
            *S9 = P + 9 * SZ;
    // S2 = M^2 ; S4 = 2M^2 - I (T2^T)
    k_gemm512<<<64, 256, 0, stream>>>(S1, S1, S2, S4, 1, nullptr, nullptr, nullptr, nullptr);
    // S3 = M^3 ; S7 = 4M^3 - 3M (T3^T)  ||  S5 = (T2^T)^2
    k_gemm512<<<128, 256, 0, stream>>>(S1, S2, S3, S7, 2, S1, S4, S4, S5);
    // S6 = (T2^T)^3  ||  S8 = (T3^T)^2
    k_gemm512<<<128, 256, 0, stream>>>(S4, S5, S6, nullptr, 0, nullptr, S7, S7, S8);
    // S9 = (T3^T)^3
    k_gemm512<<<64, 256, 0, stream>>>(S7, S8, S9, nullptr, 0, nullptr, nullptr, nullptr, nullptr);

    if (use_xbf)
        k_main<true><<<768, 512, 0, stream>>>(x, xbf, P, Wq, mlpb, out);
    else
        k_main<false><<<768, 512, 0, stream>>>(x, nullptr, P, Wq, mlpb, out);
    (void)in_sizes; (void)n_in; (void)out_size;
}

// Round 9
// 459.498 us; speedup vs baseline: 1.2583x; 1.1623x over previous
//
#include <hip/hip_runtime.h>
#include <hip/hip_bf16.h>

typedef unsigned short ushortT;
typedef unsigned int uintT;
typedef __attribute__((ext_vector_type(8))) short bf16x8;
typedef __attribute__((ext_vector_type(4))) float f32x4;
typedef __attribute__((ext_vector_type(4))) unsigned short us4;

__device__ __forceinline__ ushortT f2bf(float f) {
    union { float f; uintT u; } x; x.f = f;
    uintT r = x.u + 0x7fffu + ((x.u >> 16) & 1u);
    return (ushortT)(r >> 16);
}
__device__ __forceinline__ float bf2f(ushortT u) {
    union { uintT u; float f; } x; x.u = ((uintT)u) << 16; return x.f;
}

#define ZLD 260   // Zt row stride: 256 v-chunk + 4 pad (verified 0-conflict family)

// ---------------------------------------------------------------------------
// K0: column-softmax of W1/W2, e = emb @ sW, row-normalize.  grid=2 (e1, e2)
// ---------------------------------------------------------------------------
__global__ __launch_bounds__(256) void k_embed(const float* __restrict__ emb,
                                               const float* __restrict__ W1,
                                               const float* __restrict__ W2,
                                               float* __restrict__ e1,
                                               float* __restrict__ e2) {
    __shared__ float sW[800];
    __shared__ float sWs[800];
    const float* W = (blockIdx.x == 0) ? W1 : W2;
    float* e = (blockIdx.x == 0) ? e1 : e2;
    int tid = threadIdx.x;
    for (int i = tid; i < 800; i += 256) sW[i] = W[i];
    __syncthreads();
    if (tid < 20) {
        float mx = -1e30f;
        for (int i = 0; i < 40; ++i) mx = fmaxf(mx, sW[i * 20 + tid]);
        float s = 0.f;
        for (int i = 0; i < 40; ++i) s += __expf(sW[i * 20 + tid] - mx);
        float inv = 1.f / s;
        for (int i = 0; i < 40; ++i) sWs[i * 20 + tid] = __expf(sW[i * 20 + tid] - mx) * inv;
    }
    __syncthreads();
    for (int row = tid; row < 512; row += 256) {
        float acc[20];
        #pragma unroll
        for (int j = 0; j < 20; ++j) acc[j] = 0.f;
        for (int i = 0; i < 40; ++i) {
            float ev = emb[row * 40 + i];
            #pragma unroll
            for (int j = 0; j < 20; ++j) acc[j] += ev * sWs[i * 20 + j];
        }
        float s = 0.f;
        #pragma unroll
        for (int j = 0; j < 20; ++j) s += acc[j] * acc[j];
        float scale = 1.f / (sqrtf(s) + 1e-8f);
        #pragma unroll
        for (int j = 0; j < 20; ++j) e[row * 20 + j] = acc[j] * scale;
    }
}

// ---------------------------------------------------------------------------
// K1: A[v][w] = adj>0 ? e1[v].e2[w] + adj : 9e-15 ; d[v] = 1/sqrt(rowsum)
// ---------------------------------------------------------------------------
__global__ __launch_bounds__(256) void k_adj(const float* __restrict__ adj,
                                             const float* __restrict__ e1,
                                             const float* __restrict__ e2,
                                             float* __restrict__ A,
                                             float* __restrict__ d) {
    int v = blockIdx.x, tid = threadIdx.x;
    __shared__ float ev[20];
    if (tid < 20) ev[tid] = e1[v * 20 + tid];
    __syncthreads();
    float local = 0.f;
    for (int w = tid; w < 512; w += 256) {
        float dot = 0.f;
        #pragma unroll
        for (int j = 0; j < 20; ++j) dot += ev[j] * e2[w * 20 + j];
        float av = adj[v * 512 + w];
        float Av = (av > 0.f) ? (dot + av) : 9e-15f;
        A[v * 512 + w] = Av;
        local += Av;
    }
    __shared__ float red[256];
    red[tid] = local;
    __syncthreads();
    for (int s = 128; s > 0; s >>= 1) {
        if (tid < s) red[tid] += red[tid + s];
        __syncthreads();
    }
    if (tid == 0) d[v] = 1.f / sqrtf(red[0]);
}

// ---------------------------------------------------------------------------
// K2: P slot1 = M[w][v] = Ls^T = -d[v]*d[w]*A[v][w]  (bf16)
// ---------------------------------------------------------------------------
__global__ __launch_bounds__(256) void k_m(const float* __restrict__ A,
                                           const float* __restrict__ d,
                                           ushortT* __restrict__ P) {
    int w = blockIdx.x, tid = threadIdx.x;
    float dw = d[w];
    for (int v = tid; v < 512; v += 256) {
        float val = -d[v] * dw * A[v * 512 + w];
        P[512 * 512 + w * 512 + v] = f2bf(val);
    }
}

// ---------------------------------------------------------------------------
// K3: merged prep. Blocks 0..159: Wq build. Blocks 160+: x -> xbf convert.
// ---------------------------------------------------------------------------
__global__ __launch_bounds__(256) void k_prep(const float* __restrict__ x,
                                              ushortT* __restrict__ xbf,
                                              const float* __restrict__ mlp_w,
                                              ushortT* __restrict__ Wq) {
    int bx = blockIdx.x;
    if (bx < 160) {
        int idx = bx * 256 + threadIdx.x;
        if (idx >= 10 * 64 * 64) return;
        int q = idx >> 12, rem = idx & 4095, o = rem >> 6, c = rem & 63;
        float v;
        if (q == 0) {
            v = 0.f;
            #pragma unroll
            for (int k = 0; k < 4; ++k) v += mlp_w[o * 832 + k * 64 + c];
        } else {
            v = mlp_w[o * 832 + (q + 3) * 64 + c];
        }
        Wq[idx] = f2bf(v);
    } else {
        size_t i = (size_t)(bx - 160) * 256 + threadIdx.x;
        int c = (int)(i & 15) * 4;
        int v = (int)((i >> 4) & 511);
        int bt = (int)(i >> 13);            // b*12 + t
        int b = bt / 12, t = bt - b * 12;
        f32x4 f = *(const f32x4*)(x + (((size_t)b * 512 + v) * 12 + t) * 64 + c);
        us4 o = { f2bf(f[0]), f2bf(f[1]), f2bf(f[2]), f2bf(f[3]) };
        *(us4*)(xbf + ((size_t)bt * 512 + v) * 64 + c) = o;
    }
}

// ---------------------------------------------------------------------------
// 512x512x512 bf16 MFMA GEMM (+Chebyshev epilogue). Supports a second
// independent GEMM in blocks 64..127 (A2/B2/out3, mode 0).
// ---------------------------------------------------------------------------
__global__ __launch_bounds__(256) void k_gemm512(const ushortT* __restrict__ A,
                                                 const ushortT* __restrict__ B,
                                                 ushortT* __restrict__ out1,
                                                 ushortT* __restrict__ out2,
                                                 int mode,
                                                 const ushortT* __restrict__ aux,
                                                 const ushortT* __restrict__ A2,
                                                 const ushortT* __restrict__ B2,
                                                 ushortT* __restrict__ out3) {
    int bx = blockIdx.x;
    if (bx >= 64) { A = A2; B = B2; out1 = out3; out2 = nullptr; mode = 0; bx -= 64; }
    int wave = threadIdx.x >> 6, lane = threadIdx.x & 63;
    int lr = lane & 15, lg = lane >> 4;
    int mbase = (bx >> 3) * 64;
    int nbase = (bx & 7) * 64 + wave * 16;
    f32x4 acc[4] = {};
    for (int kk = 0; kk < 16; ++kk) {
        int k0 = kk * 32 + lg * 8;
        bf16x8 bfr;
        #pragma unroll
        for (int j = 0; j < 8; ++j) bfr[j] = (short)B[(k0 + j) * 512 + nbase + lr];
        #pragma unroll
        for (int wt = 0; wt < 4; ++wt) {
            bf16x8 af = *(const bf16x8*)(A + (mbase + wt * 16 + lr) * 512 + k0);
            acc[wt] = __builtin_amdgcn_mfma_f32_16x16x32_bf16(af, bfr, acc[wt], 0, 0, 0);
        }
    }
    #pragma unroll
    for (int wt = 0; wt < 4; ++wt)
        #pragma unroll
        for (int r = 0; r < 4; ++r) {
            int row = mbase + wt * 16 + lg * 4 + r;
            int col = nbase + lr;
            float v = acc[wt][r];
            out1[row * 512 + col] = f2bf(v);
            if (mode == 1) out2[row * 512 + col] = f2bf(2.f * v - (row == col ? 1.f : 0.f));
            else if (mode == 2) out2[row * 512 + col] = f2bf(4.f * v - 3.f * bf2f(aux[row * 512 + col]));
        }
}

// ---------------------------------------------------------------------------
// Main fused kernel v9:  out = relu(x + bias + sum_q P_q @ (X @ Wq^T))
//   Fat-wave redesign: 256-thread blocks, 4 waves x 64 output rows (4 m-tiles)
//   -> halves per-CU LDS-read instruction count (the hidden bound).
//   Phase-separated (zphase; barrier; GEMM; barrier) per (q, 256-v chunk).
//   A-ring depth-2-kk with cross-item refill; X prefetched one item ahead.
//   (256,2) => 8 waves/CU => 256-VGPR cap: no spill at ~175 VGPR.
// ---------------------------------------------------------------------------
template<bool XBF>
__global__ __launch_bounds__(256, 2) void k_main(const float* __restrict__ x,
                                                 const ushortT* __restrict__ xbf,
                                                 const ushortT* __restrict__ P,
                                                 const ushortT* __restrict__ Wq,
                                                 const float* __restrict__ bias,
                                                 float* __restrict__ out) {
    __shared__ ushortT Zt[64 * ZLD];   // Z^T[o][v-in-chunk]
    const int SZ = 512 * 512;
    // XCD-aware swizzle: slots 0-3 -> half 0, slots 4-7 -> half 1, so each
    // half's P rows live in 4 XCDs' L2s.
    int bid = blockIdx.x;
    int slot = bid & 7, idx = bid >> 3;
    int half = slot >> 2;
    int bt = idx * 4 + (slot & 3);        // 0..383 = b*12 + t
    int b = bt / 12, tt = bt - b * 12;
    int tid = threadIdx.x, wave = tid >> 6, lane = tid & 63;
    int lr = lane & 15, lg = lane >> 4;
    int wbase = half * 256 + wave * 64;   // wave's 64 output rows (4 m-tiles)
    int vzb = wave * 64;                  // wave's 64 producer v-rows in chunk

    const ushortT* xq = xbf + (size_t)bt * 512 * 64;
    const float*   xqf = x + ((size_t)b * 512 * 12 + tt) * 64;

    f32x4 oacc[4][4] = {};   // [m-tile][o-tile]
    bf16x8 aR[2][4];         // A ring, depth 2 kk, 4 m-tiles
    bf16x8 xn[4][2];         // X prefetch for next zphase

    // ---- X fragment load for chunk ch into xn ----
    auto xload = [&](int ch) {
        #pragma unroll
        for (int vt = 0; vt < 4; ++vt) {
            int vrow = ch * 256 + vzb + vt * 16 + lr;
            if (XBF) {
                xn[vt][0] = *(const bf16x8*)(xq + vrow * 64 + lg * 8);
                xn[vt][1] = *(const bf16x8*)(xq + vrow * 64 + 32 + lg * 8);
            } else {
                const float* px = xqf + (size_t)vrow * 768 + lg * 8;
                f32x4 f0 = *(const f32x4*)px;
                f32x4 f1 = *(const f32x4*)(px + 4);
                f32x4 f2 = *(const f32x4*)(px + 32);
                f32x4 f3 = *(const f32x4*)(px + 36);
                bf16x8 v0, v1;
                v0[0] = (short)f2bf(f0[0]); v0[1] = (short)f2bf(f0[1]);
                v0[2] = (short)f2bf(f0[2]); v0[3] = (short)f2bf(f0[3]);
                v0[4] = (short)f2bf(f1[0]); v0[5] = (short)f2bf(f1[1]);
                v0[6] = (short)f2bf(f1[2]); v0[7] = (short)f2bf(f1[3]);
                v1[0] = (short)f2bf(f2[0]); v1[1] = (short)f2bf(f2[1]);
                v1[2] = (short)f2bf(f2[2]); v1[3] = (short)f2bf(f2[3]);
                v1[4] = (short)f2bf(f3[0]); v1[5] = (short)f2bf(f3[1]);
                v1[6] = (short)f2bf(f3[2]); v1[7] = (short)f2bf(f3[3]);
                xn[vt][0] = v0;
                xn[vt][1] = v1;
            }
        }
    };

    // ---- z-compute from xn into Zt: rows vzb..vzb+64 of (X @ Wq^T)^T ----
    auto zphase = [&](int q) {
        const ushortT* wqp = Wq + q * 4096;
        #pragma unroll
        for (int vt = 0; vt < 4; ++vt) {
            #pragma unroll
            for (int ot = 0; ot < 4; ++ot) {
                int o = ot * 16 + lr;
                bf16x8 wf0 = *(const bf16x8*)(wqp + o * 64 + lg * 8);
                bf16x8 wf1 = *(const bf16x8*)(wqp + o * 64 + 32 + lg * 8);
                f32x4 z = {};
                z = __builtin_amdgcn_mfma_f32_16x16x32_bf16(xn[vt][0], wf0, z, 0, 0, 0);
                z = __builtin_amdgcn_mfma_f32_16x16x32_bf16(xn[vt][1], wf1, z, 0, 0, 0);
                us4 pk = { f2bf(z[0]), f2bf(z[1]), f2bf(z[2]), f2bf(z[3]) };
                *(us4*)&Zt[o * ZLD + vzb + vt * 16 + lg * 4] = pk;
            }
        }
    };

    // P fragment row pointer for item j = (q = 1+(j>>1), ch = j&1), m-tile mt
    auto pptr = [&](int j, int mt) -> const ushortT* {
        int q = 1 + (j >> 1), ch = j & 1;
        return P + (size_t)q * SZ + (size_t)(wbase + mt * 16 + lr) * 512
                 + ch * 256 + lg * 8;
    };

    // ---- prologue ----
    #pragma unroll
    for (int mt = 0; mt < 4; ++mt) {      // ring prefill: item 0, kk 0..1
        aR[0][mt] = *(const bf16x8*)(pptr(0, mt));
        aR[1][mt] = *(const bf16x8*)(pptr(0, mt) + 32);
    }
    xload(half);                           // X for q0's needed chunk
    zphase(0);
    xload(0);                              // X for item 0 (q1, ch0)
    __syncthreads();
    // oacc init = Z_0 rows for our w (identity support)
    #pragma unroll
    for (int mt = 0; mt < 4; ++mt)
        #pragma unroll
        for (int ot = 0; ot < 4; ++ot) {
            int o = ot * 16 + lr;
            us4 z4 = *(const us4*)&Zt[o * ZLD + wave * 64 + mt * 16 + lg * 4];
            oacc[mt][ot][0] = bf2f(z4[0]);
            oacc[mt][ot][1] = bf2f(z4[1]);
            oacc[mt][ot][2] = bf2f(z4[2]);
            oacc[mt][ot][3] = bf2f(z4[3]);
        }
    __syncthreads();

    // ---- 18 items: zphase -> barrier -> GEMM(+ring refill, X prefetch) ----
    #pragma unroll 1
    for (int j = 0; j < 18; ++j) {
        int q = 1 + (j >> 1);
        zphase(q);
        int jn = (j < 17) ? j + 1 : 17;
        xload(jn & 1);                     // X for next item's zphase
        __syncthreads();

        const ushortT* pc0 = pptr(j, 0);
        const ushortT* pc1 = pptr(j, 1);
        const ushortT* pc2 = pptr(j, 2);
        const ushortT* pc3 = pptr(j, 3);
        const ushortT* pn0 = pptr(jn, 0);
        const ushortT* pn1 = pptr(jn, 1);
        const ushortT* pn2 = pptr(jn, 2);
        const ushortT* pn3 = pptr(jn, 3);
        #pragma unroll
        for (int kk = 0; kk < 8; ++kk) {
            const int s = kk & 1;
            int vb = kk * 32 + lg * 8;
            bf16x8 b0 = *(const bf16x8*)&Zt[(0 * 16 + lr) * ZLD + vb];
            bf16x8 b1 = *(const bf16x8*)&Zt[(1 * 16 + lr) * ZLD + vb];
            bf16x8 b2 = *(const bf16x8*)&Zt[(2 * 16 + lr) * ZLD + vb];
            bf16x8 b3 = *(const bf16x8*)&Zt[(3 * 16 + lr) * ZLD + vb];
            oacc[0][0] = __builtin_amdgcn_mfma_f32_16x16x32_bf16(aR[s][0], b0, oacc[0][0], 0, 0, 0);
            oacc[1][0] = __builtin_amdgcn_mfma_f32_16x16x32_bf16(aR[s][1], b0, oacc[1][0], 0, 0, 0);
            oacc[2][0] = __builtin_amdgcn_mfma_f32_16x16x32_bf16(aR[s][2], b0, oacc[2][0], 0, 0, 0);
            oacc[3][0] = __builtin_amdgcn_mfma_f32_16x16x32_bf16(aR[s][3], b0, oacc[3][0], 0, 0, 0);
            oacc[0][1] = __builtin_amdgcn_mfma_f32_16x16x32_bf16(aR[s][0], b1, oacc[0][1], 0, 0, 0);
            oacc[1][1] = __builtin_amdgcn_mfma_f32_16x16x32_bf16(aR[s][1], b1, oacc[1][1], 0, 0, 0);
            oacc[2][1] = __builtin_amdgcn_mfma_f32_16x16x32_bf16(aR[s][2], b1, oacc[2][1], 0, 0, 0);
            oacc[3][1] = __builtin_amdgcn_mfma_f32_16x16x32_bf16(aR[s][3], b1, oacc[3][1], 0, 0, 0);
            oacc[0][2] = __builtin_amdgcn_mfma_f32_16x16x32_bf16(aR[s][0], b2, oacc[0][2], 0, 0, 0);
            oacc[1][2] = __builtin_amdgcn_mfma_f32_16x16x32_bf16(aR[s][1], b2, oacc[1][2], 0, 0, 0);
            oacc[2][2] = __builtin_amdgcn_mfma_f32_16x16x32_bf16(aR[s][2], b2, oacc[2][2], 0, 0, 0);
            oacc[3][2] = __builtin_amdgcn_mfma_f32_16x16x32_bf16(aR[s][3], b2, oacc[3][2], 0, 0, 0);
            oacc[0][3] = __builtin_amdgcn_mfma_f32_16x16x32_bf16(aR[s][0], b3, oacc[0][3], 0, 0, 0);
            oacc[1][3] = __builtin_amdgcn_mfma_f32_16x16x32_bf16(aR[s][1], b3, oacc[1][3], 0, 0, 0);
            oacc[2][3] = __builtin_amdgcn_mfma_f32_16x16x32_bf16(aR[s][2], b3, oacc[2][3], 0, 0, 0);
            oacc[3][3] = __builtin_amdgcn_mfma_f32_16x16x32_bf16(aR[s][3], b3, oacc[3][3], 0, 0, 0);
            if (kk < 6) {
                aR[s][0] = *(const bf16x8*)(pc0 + (kk + 2) * 32);
                aR[s][1] = *(const bf16x8*)(pc1 + (kk + 2) * 32);
                aR[s][2] = *(const bf16x8*)(pc2 + (kk + 2) * 32);
                aR[s][3] = *(const bf16x8*)(pc3 + (kk + 2) * 32);
            } else {
                aR[s][0] = *(const bf16x8*)(pn0 + (kk - 6) * 32);
                aR[s][1] = *(const bf16x8*)(pn1 + (kk - 6) * 32);
                aR[s][2] = *(const bf16x8*)(pn2 + (kk - 6) * 32);
                aR[s][3] = *(const bf16x8*)(pn3 + (kk - 6) * 32);
            }
        }
        __syncthreads();
    }

    // ---- epilogue: residual + bias + relu, fp32 out ----
    #pragma unroll
    for (int mt = 0; mt < 4; ++mt)
        #pragma unroll
        for (int ot = 0; ot < 4; ++ot)
            #pragma unroll
            for (int r = 0; r < 4; ++r) {
                int w = wbase + mt * 16 + lg * 4 + r;
                int o = ot * 16 + lr;
                size_t oi = (((size_t)b * 512 + w) * 12 + tt) * 64 + o;
                float v = oacc[mt][ot][r] + x[oi] + bias[o];
                out[oi] = (v > 0.f) ? v : 0.f;
            }
}

// ---------------------------------------------------------------------------
extern "C" void kernel_launch(void* const* d_in, const int* in_sizes, int n_in,
                              void* d_out, int out_size, void* d_ws, size_t ws_size,
                              hipStream_t stream) {
    const float* x    = (const float*)d_in[0];
    const float* adj  = (const float*)d_in[1];
    const float* emb  = (const float*)d_in[2];
    const float* W1   = (const float*)d_in[3];
    const float* W2   = (const float*)d_in[4];
    const float* mlpw = (const float*)d_in[5];
    const float* mlpb = (const float*)d_in[6];
    float* out = (float*)d_out;

    char* ws = (char*)d_ws;
    float*   e1   = (float*)(ws + 0);
    float*   e2   = (float*)(ws + 65536);
    float*   A    = (float*)(ws + 131072);
    float*   dvec = (float*)(ws + 1179648);
    ushortT* P    = (ushortT*)(ws + 1183744);            // [10][512][512] bf16 (slot0 unused)
    ushortT* Wq   = (ushortT*)(ws + 6426624);            // [10][64][64]  bf16
    ushortT* xbf  = (ushortT*)(ws + 6508544);            // [b][t][512][64] bf16 = 24MB
    const size_t WS_NEED = 6508544 + (size_t)32 * 12 * 512 * 64 * 2;
    const bool use_xbf = (ws_size >= WS_NEED);

    k_embed<<<2, 256, 0, stream>>>(emb, W1, W2, e1, e2);
    k_adj<<<512, 256, 0, stream>>>(adj, e1, e2, A, dvec);
    k_m<<<512, 256, 0, stream>>>(A, dvec, P);
    k_prep<<<use_xbf ? 12448 : 160, 256, 0, stream>>>(x, xbf, mlpw, Wq);

    const int SZ = 512 * 512;
    ushortT *S1 = P + 1 * SZ, *S2 = P + 2 * SZ, *S3 = P + 3 * SZ, *S4 = P + 4 * SZ,
            *S5 = P + 5 * SZ, *S6 = P + 6 * SZ, *S7 = P + 7 * SZ, *S8 = P + 8 * SZ,
            *S9 = P + 9 * SZ;
    // S2 = M^2 ; S4 = 2M^2 - I (T2^T)
    k_gemm512<<<64, 256, 0, stream>>>(S1, S1, S2, S4, 1, nullptr, nullptr, nullptr, nullptr);
    // S3 = M^3 ; S7 = 4M^3 - 3M (T3^T)  ||  S5 = (T2^T)^2
    k_gemm512<<<128, 256, 0, stream>>>(S1, S2, S3, S7, 2, S1, S4, S4, S5);
    // S6 = (T2^T)^3  ||  S8 = (T3^T)^2
    k_gemm512<<<128, 256, 0, stream>>>(S4, S5, S6, nullptr, 0, nullptr, S7, S7, S8);
    // S9 = (T3^T)^3
    k_gemm512<<<64, 256, 0, stream>>>(S7, S8, S9, nullptr, 0, nullptr, nullptr, nullptr, nullptr);

    if (use_xbf)
        k_main<true><<<768, 256, 0, stream>>>(x, xbf, P, Wq, mlpb, out);
    else
        k_main<false><<<768, 256, 0, stream>>>(x, nullptr, P, Wq, mlpb, out);
    (void)in_sizes; (void)n_in; (void)out_size;
}

// Round 10
// 421.922 us; speedup vs baseline: 1.3704x; 1.0891x over previous
//
#include <hip/hip_runtime.h>
#include <hip/hip_bf16.h>

typedef unsigned short ushortT;
typedef unsigned int uintT;
typedef __attribute__((ext_vector_type(8))) short bf16x8;
typedef __attribute__((ext_vector_type(4))) float f32x4;
typedef __attribute__((ext_vector_type(4))) unsigned short us4;
typedef __attribute__((ext_vector_type(8))) unsigned short us8;

__device__ __forceinline__ ushortT f2bf(float f) {
    union { float f; uintT u; } x; x.f = f;
    uintT r = x.u + 0x7fffu + ((x.u >> 16) & 1u);
    return (ushortT)(r >> 16);
}
__device__ __forceinline__ float bf2f(ushortT u) {
    union { uintT u; float f; } x; x.u = ((uintT)u) << 16; return x.f;
}

#define ZLD 260      // k_z LDS row stride (0-conflict family)
#define KTOT 5120    // K = 10 q * 512 v

// ---------------------------------------------------------------------------
// K0: column-softmax of W1/W2, e = emb @ sW, row-normalize.  grid=2 (e1, e2)
// ---------------------------------------------------------------------------
__global__ __launch_bounds__(256) void k_embed(const float* __restrict__ emb,
                                               const float* __restrict__ W1,
                                               const float* __restrict__ W2,
                                               float* __restrict__ e1,
                                               float* __restrict__ e2) {
    __shared__ float sW[800];
    __shared__ float sWs[800];
    const float* W = (blockIdx.x == 0) ? W1 : W2;
    float* e = (blockIdx.x == 0) ? e1 : e2;
    int tid = threadIdx.x;
    for (int i = tid; i < 800; i += 256) sW[i] = W[i];
    __syncthreads();
    if (tid < 20) {
        float mx = -1e30f;
        for (int i = 0; i < 40; ++i) mx = fmaxf(mx, sW[i * 20 + tid]);
        float s = 0.f;
        for (int i = 0; i < 40; ++i) s += __expf(sW[i * 20 + tid] - mx);
        float inv = 1.f / s;
        for (int i = 0; i < 40; ++i) sWs[i * 20 + tid] = __expf(sW[i * 20 + tid] - mx) * inv;
    }
    __syncthreads();
    for (int row = tid; row < 512; row += 256) {
        float acc[20];
        #pragma unroll
        for (int j = 0; j < 20; ++j) acc[j] = 0.f;
        for (int i = 0; i < 40; ++i) {
            float ev = emb[row * 40 + i];
            #pragma unroll
            for (int j = 0; j < 20; ++j) acc[j] += ev * sWs[i * 20 + j];
        }
        float s = 0.f;
        #pragma unroll
        for (int j = 0; j < 20; ++j) s += acc[j] * acc[j];
        float scale = 1.f / (sqrtf(s) + 1e-8f);
        #pragma unroll
        for (int j = 0; j < 20; ++j) e[row * 20 + j] = acc[j] * scale;
    }
}

// ---------------------------------------------------------------------------
// K1: A[v][w] = adj>0 ? e1[v].e2[w] + adj : 9e-15 ; d[v] = 1/sqrt(rowsum)
// ---------------------------------------------------------------------------
__global__ __launch_bounds__(256) void k_adj(const float* __restrict__ adj,
                                             const float* __restrict__ e1,
                                             const float* __restrict__ e2,
                                             float* __restrict__ A,
                                             float* __restrict__ d) {
    int v = blockIdx.x, tid = threadIdx.x;
    __shared__ float ev[20];
    if (tid < 20) ev[tid] = e1[v * 20 + tid];
    __syncthreads();
    float local = 0.f;
    for (int w = tid; w < 512; w += 256) {
        float dot = 0.f;
        #pragma unroll
        for (int j = 0; j < 20; ++j) dot += ev[j] * e2[w * 20 + j];
        float av = adj[v * 512 + w];
        float Av = (av > 0.f) ? (dot + av) : 9e-15f;
        A[v * 512 + w] = Av;
        local += Av;
    }
    __shared__ float red[256];
    red[tid] = local;
    __syncthreads();
    for (int s = 128; s > 0; s >>= 1) {
        if (tid < s) red[tid] += red[tid + s];
        __syncthreads();
    }
    if (tid == 0) d[v] = 1.f / sqrtf(red[0]);
}

// ---------------------------------------------------------------------------
// K2: P slot0 = I ; slot1 = M[w][v] = Ls^T = -d[v]*d[w]*A[v][w]  (bf16)
// ---------------------------------------------------------------------------
__global__ __launch_bounds__(256) void k_m(const float* __restrict__ A,
                                           const float* __restrict__ d,
                                           ushortT* __restrict__ P) {
    int w = blockIdx.x, tid = threadIdx.x;
    float dw = d[w];
    for (int v = tid; v < 512; v += 256) {
        float val = -d[v] * dw * A[v * 512 + w];
        P[512 * 512 + w * 512 + v] = f2bf(val);
        P[w * 512 + v] = (v == w) ? (ushortT)0x3F80 : (ushortT)0;
    }
}

// ---------------------------------------------------------------------------
// K3: per-q MLP weights. q=0: sum of mlp_w blocks 0..3 ; q>=1: block q+3.
// ---------------------------------------------------------------------------
__global__ __launch_bounds__(256) void k_w(const float* __restrict__ mlp_w,
                                           ushortT* __restrict__ Wq) {
    int idx = blockIdx.x * 256 + threadIdx.x;
    if (idx >= 10 * 64 * 64) return;
    int q = idx >> 12, rem = idx & 4095, o = rem >> 6, c = rem & 63;
    float v;
    if (q == 0) {
        v = 0.f;
        #pragma unroll
        for (int k = 0; k < 4; ++k) v += mlp_w[o * 832 + k * 64 + c];
    } else {
        v = mlp_w[o * 832 + (q + 3) * 64 + c];
    }
    Wq[idx] = f2bf(v);
}

// ---------------------------------------------------------------------------
// 512x512x512 bf16 MFMA GEMM (+Chebyshev epilogue). Supports a second
// independent GEMM in blocks 64..127 (A2/B2/out3, mode 0).
// ---------------------------------------------------------------------------
__global__ __launch_bounds__(256) void k_gemm512(const ushortT* __restrict__ A,
                                                 const ushortT* __restrict__ B,
                                                 ushortT* __restrict__ out1,
                                                 ushortT* __restrict__ out2,
                                                 int mode,
                                                 const ushortT* __restrict__ aux,
                                                 const ushortT* __restrict__ A2,
                                                 const ushortT* __restrict__ B2,
                                                 ushortT* __restrict__ out3) {
    int bx = blockIdx.x;
    if (bx >= 64) { A = A2; B = B2; out1 = out3; out2 = nullptr; mode = 0; bx -= 64; }
    int wave = threadIdx.x >> 6, lane = threadIdx.x & 63;
    int lr = lane & 15, lg = lane >> 4;
    int mbase = (bx >> 3) * 64;
    int nbase = (bx & 7) * 64 + wave * 16;
    f32x4 acc[4] = {};
    for (int kk = 0; kk < 16; ++kk) {
        int k0 = kk * 32 + lg * 8;
        bf16x8 bfr;
        #pragma unroll
        for (int j = 0; j < 8; ++j) bfr[j] = (short)B[(k0 + j) * 512 + nbase + lr];
        #pragma unroll
        for (int wt = 0; wt < 4; ++wt) {
            bf16x8 af = *(const bf16x8*)(A + (mbase + wt * 16 + lr) * 512 + k0);
            acc[wt] = __builtin_amdgcn_mfma_f32_16x16x32_bf16(af, bfr, acc[wt], 0, 0, 0);
        }
    }
    #pragma unroll
    for (int wt = 0; wt < 4; ++wt)
        #pragma unroll
        for (int r = 0; r < 4; ++r) {
            int row = mbase + wt * 16 + lg * 4 + r;
            int col = nbase + lr;
            float v = acc[wt][r];
            out1[row * 512 + col] = f2bf(v);
            if (mode == 1) out2[row * 512 + col] = f2bf(2.f * v - (row == col ? 1.f : 0.f));
            else if (mode == 2) out2[row * 512 + col] = f2bf(4.f * v - 3.f * bf2f(aux[row * 512 + col]));
        }
}

// ---------------------------------------------------------------------------
// k_z: build B' = Z^T.  Z[n = btl*64+o][k = q*512+v] = sum_c x[bt,v,c]*Wq[o,c]
// Block = (btl, v-chunk of 256). 4 waves x 64 v-rows. Per q: 32 MFMA/wave ->
// LDS [64 o][260] -> coalesced 16B row stream to global.
// ---------------------------------------------------------------------------
__global__ __launch_bounds__(256) void k_z(const float* __restrict__ x,
                                           const ushortT* __restrict__ Wq,
                                           ushortT* __restrict__ Z,
                                           int slab0) {
    __shared__ ushortT Zl[64 * ZLD];
    int bid = blockIdx.x;
    int btl = bid >> 1, chunk = bid & 1;
    int bt = slab0 + btl;
    int b = bt / 12, t = bt - b * 12;
    int tid = threadIdx.x, wave = tid >> 6, lane = tid & 63;
    int lr = lane & 15, lg = lane >> 4;

    // ---- load + convert this wave's 64 X rows (v) into registers ----
    bf16x8 xn[4][2];
    const float* xb = x + ((size_t)b * 512 * 12 + t) * 64;
    #pragma unroll
    for (int vt = 0; vt < 4; ++vt) {
        int vrow = chunk * 256 + wave * 64 + vt * 16 + lr;
        const float* px = xb + (size_t)vrow * 768 + lg * 8;
        f32x4 f0 = *(const f32x4*)px;
        f32x4 f1 = *(const f32x4*)(px + 4);
        f32x4 f2 = *(const f32x4*)(px + 32);
        f32x4 f3 = *(const f32x4*)(px + 36);
        bf16x8 v0, v1;
        v0[0] = (short)f2bf(f0[0]); v0[1] = (short)f2bf(f0[1]);
        v0[2] = (short)f2bf(f0[2]); v0[3] = (short)f2bf(f0[3]);
        v0[4] = (short)f2bf(f1[0]); v0[5] = (short)f2bf(f1[1]);
        v0[6] = (short)f2bf(f1[2]); v0[7] = (short)f2bf(f1[3]);
        v1[0] = (short)f2bf(f2[0]); v1[1] = (short)f2bf(f2[1]);
        v1[2] = (short)f2bf(f2[2]); v1[3] = (short)f2bf(f2[3]);
        v1[4] = (short)f2bf(f3[0]); v1[5] = (short)f2bf(f3[1]);
        v1[6] = (short)f2bf(f3[2]); v1[7] = (short)f2bf(f3[3]);
        xn[vt][0] = v0;
        xn[vt][1] = v1;
    }

    #pragma unroll 1
    for (int q = 0; q < 10; ++q) {
        const ushortT* wqp = Wq + q * 4096;
        #pragma unroll
        for (int ot = 0; ot < 4; ++ot) {
            int o = ot * 16 + lr;
            bf16x8 wf0 = *(const bf16x8*)(wqp + o * 64 + lg * 8);
            bf16x8 wf1 = *(const bf16x8*)(wqp + o * 64 + 32 + lg * 8);
            #pragma unroll
            for (int vt = 0; vt < 4; ++vt) {
                f32x4 z = {};
                z = __builtin_amdgcn_mfma_f32_16x16x32_bf16(xn[vt][0], wf0, z, 0, 0, 0);
                z = __builtin_amdgcn_mfma_f32_16x16x32_bf16(xn[vt][1], wf1, z, 0, 0, 0);
                us4 pk = { f2bf(z[0]), f2bf(z[1]), f2bf(z[2]), f2bf(z[3]) };
                *(us4*)&Zl[o * ZLD + wave * 64 + vt * 16 + lg * 4] = pk;
            }
        }
        __syncthreads();
        // stream LDS rows -> Z (coalesced 16B stores)
        size_t kbase = (size_t)q * 512 + chunk * 256;
        #pragma unroll
        for (int j = 0; j < 8; ++j) {
            int flat = j * 256 + tid;          // 0..2047
            int o = flat >> 5, slot = flat & 31;
            us4 lo = *(const us4*)&Zl[o * ZLD + slot * 8];
            us4 hi = *(const us4*)&Zl[o * ZLD + slot * 8 + 4];
            us8 val = { lo[0], lo[1], lo[2], lo[3], hi[0], hi[1], hi[2], hi[3] };
            *(us8*)&Z[(size_t)(btl * 64 + o) * KTOT + kbase + slot * 8] = val;
        }
        __syncthreads();
    }
}

// ---------------------------------------------------------------------------
// k_big: out' = A' (512 x 5120) @ B' (5120 x Nslab), epilogue residual+relu.
// m97-class: 128x128 tile, BK=32, dbuf LDS (32KB), global_load_lds width-16
// with XOR-swizzle involution (pre-swizzled source + swizzled ds_read_b128),
// 1 barrier/K-step, XCD-chunked block swizzle (m fastest within chunk).
// ---------------------------------------------------------------------------
__global__ __launch_bounds__(256) void k_big(const ushortT* __restrict__ P,
                                             const ushortT* __restrict__ Z,
                                             const float* __restrict__ x,
                                             const float* __restrict__ bias,
                                             float* __restrict__ out,
                                             int slab0) {
    __shared__ ushortT SA[2][4096];   // [buf][128 m x 32 k]
    __shared__ ushortT SB[2][4096];   // [buf][128 n x 32 k]
    int nwg = (int)gridDim.x;
    int bid = (int)blockIdx.x;
    int cpx = nwg >> 3;                               // blocks per XCD chunk
    int lbid = (bid & 7) * cpx + (bid >> 3);          // bijective (nwg%8==0)
    int mblk = lbid & 3;                              // m fastest -> same XCD
    int nblk = lbid >> 2;
    int mbase = mblk * 128;
    int n0 = nblk * 128;                              // slab-local col base
    int tid = threadIdx.x, wave = tid >> 6, lane = tid & 63;
    int lr = lane & 15, lg = lane >> 4;
    int wm = wave >> 1, wn = wave & 1;

    f32x4 acc[4][4] = {};

    // stage K-step kt into buffer buf (A: P rows, B: Z rows), swizzled source
    auto stage = [&](int kt, int buf) {
        int q = kt >> 4;
        int v0 = (kt & 15) * 32;
        const ushortT* Pk = P + (size_t)q * 262144 + v0;
        #pragma unroll
        for (int i = 0; i < 2; ++i) {
            int s = i * 256 + tid;          // 16B slot 0..511
            int row = s >> 2, g = s & 3;
            int gp = g ^ (row & 3);
            const ushortT* srcA = Pk + (size_t)(mbase + row) * 512 + gp * 8;
            __builtin_amdgcn_global_load_lds(srcA, &SA[buf][(i * 256 + wave * 64) * 8], 16, 0, 0);
            const ushortT* srcB = Z + (size_t)(n0 + row) * KTOT + kt * 32 + gp * 8;
            __builtin_amdgcn_global_load_lds(srcB, &SB[buf][(i * 256 + wave * 64) * 8], 16, 0, 0);
        }
    };

    stage(0, 0);
    __syncthreads();

    #pragma unroll 2
    for (int kt = 0; kt < 160; ++kt) {
        int buf = kt & 1;
        if (kt < 159) stage(kt + 1, buf ^ 1);
        bf16x8 af[4], bf[4];
        #pragma unroll
        for (int mt = 0; mt < 4; ++mt) {
            int m = wm * 64 + mt * 16 + lr;
            af[mt] = *(const bf16x8*)&SA[buf][m * 32 + ((lg ^ (m & 3)) * 8)];
        }
        #pragma unroll
        for (int nt = 0; nt < 4; ++nt) {
            int n = wn * 64 + nt * 16 + lr;
            bf[nt] = *(const bf16x8*)&SB[buf][n * 32 + ((lg ^ (n & 3)) * 8)];
        }
        #pragma unroll
        for (int mt = 0; mt < 4; ++mt)
            #pragma unroll
            for (int nt = 0; nt < 4; ++nt)
                acc[mt][nt] = __builtin_amdgcn_mfma_f32_16x16x32_bf16(af[mt], bf[nt], acc[mt][nt], 0, 0, 0);
        __syncthreads();
    }

    // ---- epilogue: residual + bias + relu ----
    #pragma unroll
    for (int mt = 0; mt < 4; ++mt)
        #pragma unroll
        for (int nt = 0; nt < 4; ++nt)
            #pragma unroll
            for (int r = 0; r < 4; ++r) {
                int m = mbase + wm * 64 + mt * 16 + lg * 4 + r;   // w
                int nf = n0 + wn * 64 + nt * 16 + lr;
                int btl = nf >> 6, o = nf & 63;
                int bt = slab0 + btl;
                int bb = bt / 12, t = bt - bb * 12;
                size_t oi = (((size_t)bb * 512 + m) * 12 + t) * 64 + o;
                float v = acc[mt][nt][r] + x[oi] + bias[o];
                out[oi] = (v > 0.f) ? v : 0.f;
            }
}

// ---------------------------------------------------------------------------
// Fallback fused kernel (R9 structure, f32 x path) — used only if ws is tiny.
// ---------------------------------------------------------------------------
__global__ __launch_bounds__(256, 2) void k_main_fb(const float* __restrict__ x,
                                                    const ushortT* __restrict__ P,
                                                    const ushortT* __restrict__ Wq,
                                                    const float* __restrict__ bias,
                                                    float* __restrict__ out) {
    __shared__ ushortT Zt[64 * ZLD];
    const int SZ = 512 * 512;
    int bid = blockIdx.x;
    int slot = bid & 7, idx = bid >> 3;
    int half = slot >> 2;
    int bt = idx * 4 + (slot & 3);
    int b = bt / 12, tt = bt - b * 12;
    int tid = threadIdx.x, wave = tid >> 6, lane = tid & 63;
    int lr = lane & 15, lg = lane >> 4;
    int wbase = half * 256 + wave * 64;
    int vzb = wave * 64;
    const float* xqf = x + ((size_t)b * 512 * 12 + tt) * 64;

    f32x4 oacc[4][4] = {};
    bf16x8 xn[4][2];

    auto xload = [&](int ch) {
        #pragma unroll
        for (int vt = 0; vt < 4; ++vt) {
            int vrow = ch * 256 + vzb + vt * 16 + lr;
            const float* px = xqf + (size_t)vrow * 768 + lg * 8;
            f32x4 f0 = *(const f32x4*)px;
            f32x4 f1 = *(const f32x4*)(px + 4);
            f32x4 f2 = *(const f32x4*)(px + 32);
            f32x4 f3 = *(const f32x4*)(px + 36);
            bf16x8 v0, v1;
            v0[0] = (short)f2bf(f0[0]); v0[1] = (short)f2bf(f0[1]);
            v0[2] = (short)f2bf(f0[2]); v0[3] = (short)f2bf(f0[3]);
            v0[4] = (short)f2bf(f1[0]); v0[5] = (short)f2bf(f1[1]);
            v0[6] = (short)f2bf(f1[2]); v0[7] = (short)f2bf(f1[3]);
            v1[0] = (short)f2bf(f2[0]); v1[1] = (short)f2bf(f2[1]);
            v1[2] = (short)f2bf(f2[2]); v1[3] = (short)f2bf(f2[3]);
            v1[4] = (short)f2bf(f3[0]); v1[5] = (short)f2bf(f3[1]);
            v1[6] = (short)f2bf(f3[2]); v1[7] = (short)f2bf(f3[3]);
            xn[vt][0] = v0;
            xn[vt][1] = v1;
        }
    };
    auto zphase = [&](int q) {
        const ushortT* wqp = Wq + q * 4096;
        #pragma unroll
        for (int vt = 0; vt < 4; ++vt)
            #pragma unroll
            for (int ot = 0; ot < 4; ++ot) {
                int o = ot * 16 + lr;
                bf16x8 wf0 = *(const bf16x8*)(wqp + o * 64 + lg * 8);
                bf16x8 wf1 = *(const bf16x8*)(wqp + o * 64 + 32 + lg * 8);
                f32x4 z = {};
                z = __builtin_amdgcn_mfma_f32_16x16x32_bf16(xn[vt][0], wf0, z, 0, 0, 0);
                z = __builtin_amdgcn_mfma_f32_16x16x32_bf16(xn[vt][1], wf1, z, 0, 0, 0);
                us4 pk = { f2bf(z[0]), f2bf(z[1]), f2bf(z[2]), f2bf(z[3]) };
                *(us4*)&Zt[o * ZLD + vzb + vt * 16 + lg * 4] = pk;
            }
    };
    auto pptr = [&](int j, int mt) -> const ushortT* {
        int q = 1 + (j >> 1), ch = j & 1;
        return P + (size_t)q * SZ + (size_t)(wbase + mt * 16 + lr) * 512 + ch * 256 + lg * 8;
    };

    xload(half);
    zphase(0);
    xload(0);
    __syncthreads();
    #pragma unroll
    for (int mt = 0; mt < 4; ++mt)
        #pragma unroll
        for (int ot = 0; ot < 4; ++ot) {
            int o = ot * 16 + lr;
            us4 z4 = *(const us4*)&Zt[o * ZLD + wave * 64 + mt * 16 + lg * 4];
            oacc[mt][ot][0] = bf2f(z4[0]);
            oacc[mt][ot][1] = bf2f(z4[1]);
            oacc[mt][ot][2] = bf2f(z4[2]);
            oacc[mt][ot][3] = bf2f(z4[3]);
        }
    __syncthreads();

    #pragma unroll 1
    for (int j = 0; j < 18; ++j) {
        int q = 1 + (j >> 1);
        zphase(q);
        int jn = (j < 17) ? j + 1 : 17;
        xload(jn & 1);
        __syncthreads();
        const ushortT* pc0 = pptr(j, 0);
        const ushortT* pc1 = pptr(j, 1);
        const ushortT* pc2 = pptr(j, 2);
        const ushortT* pc3 = pptr(j, 3);
        #pragma unroll
        for (int kk = 0; kk < 8; ++kk) {
            bf16x8 a0 = *(const bf16x8*)(pc0 + kk * 32);
            bf16x8 a1 = *(const bf16x8*)(pc1 + kk * 32);
            bf16x8 a2 = *(const bf16x8*)(pc2 + kk * 32);
            bf16x8 a3 = *(const bf16x8*)(pc3 + kk * 32);
            int vb = kk * 32 + lg * 8;
            bf16x8 b0 = *(const bf16x8*)&Zt[(0 * 16 + lr) * ZLD + vb];
            bf16x8 b1 = *(const bf16x8*)&Zt[(1 * 16 + lr) * ZLD + vb];
            bf16x8 b2 = *(const bf16x8*)&Zt[(2 * 16 + lr) * ZLD + vb];
            bf16x8 b3 = *(const bf16x8*)&Zt[(3 * 16 + lr) * ZLD + vb];
            oacc[0][0] = __builtin_amdgcn_mfma_f32_16x16x32_bf16(a0, b0, oacc[0][0], 0, 0, 0);
            oacc[1][0] = __builtin_amdgcn_mfma_f32_16x16x32_bf16(a1, b0, oacc[1][0], 0, 0, 0);
            oacc[2][0] = __builtin_amdgcn_mfma_f32_16x16x32_bf16(a2, b0, oacc[2][0], 0, 0, 0);
            oacc[3][0] = __builtin_amdgcn_mfma_f32_16x16x32_bf16(a3, b0, oacc[3][0], 0, 0, 0);
            oacc[0][1] = __builtin_amdgcn_mfma_f32_16x16x32_bf16(a0, b1, oacc[0][1], 0, 0, 0);
            oacc[1][1] = __builtin_amdgcn_mfma_f32_16x16x32_bf16(a1, b1, oacc[1][1], 0, 0, 0);
            oacc[2][1] = __builtin_amdgcn_mfma_f32_16x16x32_bf16(a2, b1, oacc[2][1], 0, 0, 0);
            oacc[3][1] = __builtin_amdgcn_mfma_f32_16x16x32_bf16(a3, b1, oacc[3][1], 0, 0, 0);
            oacc[0][2] = __builtin_amdgcn_mfma_f32_16x16x32_bf16(a0, b2, oacc[0][2], 0, 0, 0);
            oacc[1][2] = __builtin_amdgcn_mfma_f32_16x16x32_bf16(a1, b2, oacc[1][2], 0, 0, 0);
            oacc[2][2] = __builtin_amdgcn_mfma_f32_16x16x32_bf16(a2, b2, oacc[2][2], 0, 0, 0);
            oacc[3][2] = __builtin_amdgcn_mfma_f32_16x16x32_bf16(a3, b2, oacc[3][2], 0, 0, 0);
            oacc[0][3] = __builtin_amdgcn_mfma_f32_16x16x32_bf16(a0, b3, oacc[0][3], 0, 0, 0);
            oacc[1][3] = __builtin_amdgcn_mfma_f32_16x16x32_bf16(a1, b3, oacc[1][3], 0, 0, 0);
            oacc[2][3] = __builtin_amdgcn_mfma_f32_16x16x32_bf16(a2, b3, oacc[2][3], 0, 0, 0);
            oacc[3][3] = __builtin_amdgcn_mfma_f32_16x16x32_bf16(a3, b3, oacc[3][3], 0, 0, 0);
        }
        __syncthreads();
    }

    #pragma unroll
    for (int mt = 0; mt < 4; ++mt)
        #pragma unroll
        for (int ot = 0; ot < 4; ++ot)
            #pragma unroll
            for (int r = 0; r < 4; ++r) {
                int w = wbase + mt * 16 + lg * 4 + r;
                int o = ot * 16 + lr;
                size_t oi = (((size_t)b * 512 + w) * 12 + tt) * 64 + o;
                float v = oacc[mt][ot][r] + x[oi] + bias[o];
                out[oi] = (v > 0.f) ? v : 0.f;
            }
}

// ---------------------------------------------------------------------------
extern "C" void kernel_launch(void* const* d_in, const int* in_sizes, int n_in,
                              void* d_out, int out_size, void* d_ws, size_t ws_size,
                              hipStream_t stream) {
    const float* x    = (const float*)d_in[0];
    const float* adj  = (const float*)d_in[1];
    const float* emb  = (const float*)d_in[2];
    const float* W1   = (const float*)d_in[3];
    const float* W2   = (const float*)d_in[4];
    const float* mlpw = (const float*)d_in[5];
    const float* mlpb = (const float*)d_in[6];
    float* out = (float*)d_out;

    char* ws = (char*)d_ws;
    float*   e1   = (float*)(ws + 0);
    float*   e2   = (float*)(ws + 65536);
    float*   A    = (float*)(ws + 131072);
    float*   dvec = (float*)(ws + 1179648);
    ushortT* P    = (ushortT*)(ws + 1183744);   // [10][512][512] bf16 (slot0 = I)
    ushortT* Wq   = (ushortT*)(ws + 6426624);   // [10][64][64]  bf16
    ushortT* Z    = (ushortT*)(ws + 6508544);   // B' slab buffer
    const size_t ZOFF = 6508544;

    k_embed<<<2, 256, 0, stream>>>(emb, W1, W2, e1, e2);
    k_adj<<<512, 256, 0, stream>>>(adj, e1, e2, A, dvec);
    k_m<<<512, 256, 0, stream>>>(A, dvec, P);
    k_w<<<160, 256, 0, stream>>>(mlpw, Wq);

    const int SZ = 512 * 512;
    ushortT *S1 = P + 1 * SZ, *S2 = P + 2 * SZ, *S3 = P + 3 * SZ, *S4 = P + 4 * SZ,
            *S5 = P + 5 * SZ, *S6 = P + 6 * SZ, *S7 = P + 7 * SZ, *S8 = P + 8 * SZ,
            *S9 = P + 9 * SZ;
    // S2 = M^2 ; S4 = 2M^2 - I (T2^T)
    k_gemm512<<<64, 256, 0, stream>>>(S1, S1, S2, S4, 1, nullptr, nullptr, nullptr, nullptr);
    // S3 = M^3 ; S7 = 4M^3 - 3M (T3^T)  ||  S5 = (T2^T)^2
    k_gemm512<<<128, 256, 0, stream>>>(S1, S2, S3, S7, 2, S1, S4, S4, S5);
    // S6 = (T2^T)^3  ||  S8 = (T3^T)^2
    k_gemm512<<<128, 256, 0, stream>>>(S4, S5, S6, nullptr, 0, nullptr, S7, S7, S8);
    // S9 = (T3^T)^3
    k_gemm512<<<64, 256, 0, stream>>>(S7, S8, S9, nullptr, 0, nullptr, nullptr, nullptr, nullptr);

    const size_t ZFULL = (size_t)24576 * KTOT * 2;   // 251.7 MB
    int nslab = 1;
    while (nslab <= 8 && ws_size < ZOFF + ZFULL / (size_t)nslab) nslab <<= 1;

    if (nslab <= 8) {
        int btps = 384 / nslab;
        for (int s = 0; s < nslab; ++s) {
            k_z<<<btps * 2, 256, 0, stream>>>(x, Wq, Z, s * btps);
            k_big<<<btps * 2, 256, 0, stream>>>(P, Z, x, mlpb, out, s * btps);
        }
    } else {
        k_main_fb<<<768, 256, 0, stream>>>(x, P, Wq, mlpb, out);
    }
    (void)in_sizes; (void)n_in; (void)out_size;
}

// Round 11
// 327.209 us; speedup vs baseline: 1.7670x; 1.2895x over previous
//
#include <hip/hip_runtime.h>
#include <hip/hip_bf16.h>

typedef unsigned short ushortT;
typedef unsigned int uintT;
typedef __attribute__((ext_vector_type(8))) short bf16x8;
typedef __attribute__((ext_vector_type(4))) float f32x4;
typedef __attribute__((ext_vector_type(4))) unsigned short us4;
typedef __attribute__((ext_vector_type(8))) unsigned short us8;

__device__ __forceinline__ ushortT f2bf(float f) {
    union { float f; uintT u; } x; x.f = f;
    uintT r = x.u + 0x7fffu + ((x.u >> 16) & 1u);
    return (ushortT)(r >> 16);
}
__device__ __forceinline__ float bf2f(ushortT u) {
    union { uintT u; float f; } x; x.u = ((uintT)u) << 16; return x.f;
}

#define ZLD 260      // k_z LDS row stride (0-conflict family)
#define KTOT 5120    // K = 10 q * 512 v

// ---------------------------------------------------------------------------
// K0: column-softmax of W1/W2, e = emb @ sW, row-normalize.  grid=2 (e1, e2)
// ---------------------------------------------------------------------------
__global__ __launch_bounds__(256) void k_embed(const float* __restrict__ emb,
                                               const float* __restrict__ W1,
                                               const float* __restrict__ W2,
                                               float* __restrict__ e1,
                                               float* __restrict__ e2) {
    __shared__ float sW[800];
    __shared__ float sWs[800];
    const float* W = (blockIdx.x == 0) ? W1 : W2;
    float* e = (blockIdx.x == 0) ? e1 : e2;
    int tid = threadIdx.x;
    for (int i = tid; i < 800; i += 256) sW[i] = W[i];
    __syncthreads();
    if (tid < 20) {
        float mx = -1e30f;
        for (int i = 0; i < 40; ++i) mx = fmaxf(mx, sW[i * 20 + tid]);
        float s = 0.f;
        for (int i = 0; i < 40; ++i) s += __expf(sW[i * 20 + tid] - mx);
        float inv = 1.f / s;
        for (int i = 0; i < 40; ++i) sWs[i * 20 + tid] = __expf(sW[i * 20 + tid] - mx) * inv;
    }
    __syncthreads();
    for (int row = tid; row < 512; row += 256) {
        float acc[20];
        #pragma unroll
        for (int j = 0; j < 20; ++j) acc[j] = 0.f;
        for (int i = 0; i < 40; ++i) {
            float ev = emb[row * 40 + i];
            #pragma unroll
            for (int j = 0; j < 20; ++j) acc[j] += ev * sWs[i * 20 + j];
        }
        float s = 0.f;
        #pragma unroll
        for (int j = 0; j < 20; ++j) s += acc[j] * acc[j];
        float scale = 1.f / (sqrtf(s) + 1e-8f);
        #pragma unroll
        for (int j = 0; j < 20; ++j) e[row * 20 + j] = acc[j] * scale;
    }
}

// ---------------------------------------------------------------------------
// K1: A[v][w] = adj>0 ? e1[v].e2[w] + adj : 9e-15 ; d[v] = 1/sqrt(rowsum)
// ---------------------------------------------------------------------------
__global__ __launch_bounds__(256) void k_adj(const float* __restrict__ adj,
                                             const float* __restrict__ e1,
                                             const float* __restrict__ e2,
                                             float* __restrict__ A,
                                             float* __restrict__ d) {
    int v = blockIdx.x, tid = threadIdx.x;
    __shared__ float ev[20];
    if (tid < 20) ev[tid] = e1[v * 20 + tid];
    __syncthreads();
    float local = 0.f;
    for (int w = tid; w < 512; w += 256) {
        float dot = 0.f;
        #pragma unroll
        for (int j = 0; j < 20; ++j) dot += ev[j] * e2[w * 20 + j];
        float av = adj[v * 512 + w];
        float Av = (av > 0.f) ? (dot + av) : 9e-15f;
        A[v * 512 + w] = Av;
        local += Av;
    }
    __shared__ float red[256];
    red[tid] = local;
    __syncthreads();
    for (int s = 128; s > 0; s >>= 1) {
        if (tid < s) red[tid] += red[tid + s];
        __syncthreads();
    }
    if (tid == 0) d[v] = 1.f / sqrtf(red[0]);
}

// ---------------------------------------------------------------------------
// K2: P slot0 = I ; slot1 = M[w][v] = Ls^T = -d[v]*d[w]*A[v][w]  (bf16)
// ---------------------------------------------------------------------------
__global__ __launch_bounds__(256) void k_m(const float* __restrict__ A,
                                           const float* __restrict__ d,
                                           ushortT* __restrict__ P) {
    int w = blockIdx.x, tid = threadIdx.x;
    float dw = d[w];
    for (int v = tid; v < 512; v += 256) {
        float val = -d[v] * dw * A[v * 512 + w];
        P[512 * 512 + w * 512 + v] = f2bf(val);
        P[w * 512 + v] = (v == w) ? (ushortT)0x3F80 : (ushortT)0;
    }
}

// ---------------------------------------------------------------------------
// K3: per-q MLP weights. q=0: sum of mlp_w blocks 0..3 ; q>=1: block q+3.
// ---------------------------------------------------------------------------
__global__ __launch_bounds__(256) void k_w(const float* __restrict__ mlp_w,
                                           ushortT* __restrict__ Wq) {
    int idx = blockIdx.x * 256 + threadIdx.x;
    if (idx >= 10 * 64 * 64) return;
    int q = idx >> 12, rem = idx & 4095, o = rem >> 6, c = rem & 63;
    float v;
    if (q == 0) {
        v = 0.f;
        #pragma unroll
        for (int k = 0; k < 4; ++k) v += mlp_w[o * 832 + k * 64 + c];
    } else {
        v = mlp_w[o * 832 + (q + 3) * 64 + c];
    }
    Wq[idx] = f2bf(v);
}

// ---------------------------------------------------------------------------
// 512x512x512 bf16 MFMA GEMM (+Chebyshev epilogue). Supports a second
// independent GEMM in blocks 64..127 (A2/B2/out3, mode 0).
// ---------------------------------------------------------------------------
__global__ __launch_bounds__(256) void k_gemm512(const ushortT* __restrict__ A,
                                                 const ushortT* __restrict__ B,
                                                 ushortT* __restrict__ out1,
                                                 ushortT* __restrict__ out2,
                                                 int mode,
                                                 const ushortT* __restrict__ aux,
                                                 const ushortT* __restrict__ A2,
                                                 const ushortT* __restrict__ B2,
                                                 ushortT* __restrict__ out3) {
    int bx = blockIdx.x;
    if (bx >= 64) { A = A2; B = B2; out1 = out3; out2 = nullptr; mode = 0; bx -= 64; }
    int wave = threadIdx.x >> 6, lane = threadIdx.x & 63;
    int lr = lane & 15, lg = lane >> 4;
    int mbase = (bx >> 3) * 64;
    int nbase = (bx & 7) * 64 + wave * 16;
    f32x4 acc[4] = {};
    for (int kk = 0; kk < 16; ++kk) {
        int k0 = kk * 32 + lg * 8;
        bf16x8 bfr;
        #pragma unroll
        for (int j = 0; j < 8; ++j) bfr[j] = (short)B[(k0 + j) * 512 + nbase + lr];
        #pragma unroll
        for (int wt = 0; wt < 4; ++wt) {
            bf16x8 af = *(const bf16x8*)(A + (mbase + wt * 16 + lr) * 512 + k0);
            acc[wt] = __builtin_amdgcn_mfma_f32_16x16x32_bf16(af, bfr, acc[wt], 0, 0, 0);
        }
    }
    #pragma unroll
    for (int wt = 0; wt < 4; ++wt)
        #pragma unroll
        for (int r = 0; r < 4; ++r) {
            int row = mbase + wt * 16 + lg * 4 + r;
            int col = nbase + lr;
            float v = acc[wt][r];
            out1[row * 512 + col] = f2bf(v);
            if (mode == 1) out2[row * 512 + col] = f2bf(2.f * v - (row == col ? 1.f : 0.f));
            else if (mode == 2) out2[row * 512 + col] = f2bf(4.f * v - 3.f * bf2f(aux[row * 512 + col]));
        }
}

// ---------------------------------------------------------------------------
// k_z: build B' = Z^T.  Z[n = btl*64+o][k = q*512+v] = sum_c x[bt,v,c]*Wq[o,c]
// ---------------------------------------------------------------------------
__global__ __launch_bounds__(256) void k_z(const float* __restrict__ x,
                                           const ushortT* __restrict__ Wq,
                                           ushortT* __restrict__ Z,
                                           int slab0) {
    __shared__ ushortT Zl[64 * ZLD];
    int bid = blockIdx.x;
    int btl = bid >> 1, chunk = bid & 1;
    int bt = slab0 + btl;
    int b = bt / 12, t = bt - b * 12;
    int tid = threadIdx.x, wave = tid >> 6, lane = tid & 63;
    int lr = lane & 15, lg = lane >> 4;

    bf16x8 xn[4][2];
    const float* xb = x + ((size_t)b * 512 * 12 + t) * 64;
    #pragma unroll
    for (int vt = 0; vt < 4; ++vt) {
        int vrow = chunk * 256 + wave * 64 + vt * 16 + lr;
        const float* px = xb + (size_t)vrow * 768 + lg * 8;
        f32x4 f0 = *(const f32x4*)px;
        f32x4 f1 = *(const f32x4*)(px + 4);
        f32x4 f2 = *(const f32x4*)(px + 32);
        f32x4 f3 = *(const f32x4*)(px + 36);
        bf16x8 v0, v1;
        v0[0] = (short)f2bf(f0[0]); v0[1] = (short)f2bf(f0[1]);
        v0[2] = (short)f2bf(f0[2]); v0[3] = (short)f2bf(f0[3]);
        v0[4] = (short)f2bf(f1[0]); v0[5] = (short)f2bf(f1[1]);
        v0[6] = (short)f2bf(f1[2]); v0[7] = (short)f2bf(f1[3]);
        v1[0] = (short)f2bf(f2[0]); v1[1] = (short)f2bf(f2[1]);
        v1[2] = (short)f2bf(f2[2]); v1[3] = (short)f2bf(f2[3]);
        v1[4] = (short)f2bf(f3[0]); v1[5] = (short)f2bf(f3[1]);
        v1[6] = (short)f2bf(f3[2]); v1[7] = (short)f2bf(f3[3]);
        xn[vt][0] = v0;
        xn[vt][1] = v1;
    }

    #pragma unroll 1
    for (int q = 0; q < 10; ++q) {
        const ushortT* wqp = Wq + q * 4096;
        #pragma unroll
        for (int ot = 0; ot < 4; ++ot) {
            int o = ot * 16 + lr;
            bf16x8 wf0 = *(const bf16x8*)(wqp + o * 64 + lg * 8);
            bf16x8 wf1 = *(const bf16x8*)(wqp + o * 64 + 32 + lg * 8);
            #pragma unroll
            for (int vt = 0; vt < 4; ++vt) {
                f32x4 z = {};
                z = __builtin_amdgcn_mfma_f32_16x16x32_bf16(xn[vt][0], wf0, z, 0, 0, 0);
                z = __builtin_amdgcn_mfma_f32_16x16x32_bf16(xn[vt][1], wf1, z, 0, 0, 0);
                us4 pk = { f2bf(z[0]), f2bf(z[1]), f2bf(z[2]), f2bf(z[3]) };
                *(us4*)&Zl[o * ZLD + wave * 64 + vt * 16 + lg * 4] = pk;
            }
        }
        __syncthreads();
        size_t kbase = (size_t)q * 512 + chunk * 256;
        #pragma unroll
        for (int j = 0; j < 8; ++j) {
            int flat = j * 256 + tid;
            int o = flat >> 5, slot = flat & 31;
            us4 lo = *(const us4*)&Zl[o * ZLD + slot * 8];
            us4 hi = *(const us4*)&Zl[o * ZLD + slot * 8 + 4];
            us8 val = { lo[0], lo[1], lo[2], lo[3], hi[0], hi[1], hi[2], hi[3] };
            *(us8*)&Z[(size_t)(btl * 64 + o) * KTOT + kbase + slot * 8] = val;
        }
        __syncthreads();
    }
}

// ---------------------------------------------------------------------------
// k_big v2: out' = A' (512 x 5120) @ B' (5120 x N), T3/T4 counted-vmcnt
// pipeline: 3-deep LDS stage ring (48KB), raw s_barrier pairs, vmcnt(8)
// steady-state (never 0 in main loop), linear m97-style LDS layout.
// ---------------------------------------------------------------------------
__global__ __launch_bounds__(256) void k_big(const ushortT* __restrict__ P,
                                             const ushortT* __restrict__ Z,
                                             const float* __restrict__ x,
                                             const float* __restrict__ bias,
                                             float* __restrict__ out,
                                             int slab0) {
    __shared__ ushortT SA[3][4096];   // [ring][128 m x 32 k] linear
    __shared__ ushortT SB[3][4096];   // [ring][128 n x 32 k] linear
    int nwg = (int)gridDim.x;
    int bid = (int)blockIdx.x;
    int cpx = nwg >> 3;                               // blocks per XCD chunk
    int lbid = (bid & 7) * cpx + (bid >> 3);          // bijective (nwg%8==0)
    int mblk = lbid & 3;                              // m fastest -> same XCD
    int nblk = lbid >> 2;
    int mbase = mblk * 128;
    int n0 = nblk * 128;
    int tid = threadIdx.x, wave = tid >> 6, lane = tid & 63;
    int lr = lane & 15, lg = lane >> 4;
    int wm = wave >> 1, wn = wave & 1;
    int srow = tid >> 2, sg = tid & 3;                // staging row/group

    f32x4 acc[4][4] = {};

    // stage K-step kt into ring buffer buf (A: P rows, B: Z rows). Linear LDS.
    auto stage = [&](int kt, int buf) {
        int q = kt >> 4;
        int v0 = (kt & 15) * 32;
        const ushortT* Pk = P + (size_t)q * 262144 + v0 + sg * 8;
        const ushortT* Zk = Z + (size_t)kt * 32 + sg * 8;
        #pragma unroll
        for (int i = 0; i < 2; ++i) {
            int row = i * 64 + srow;
            __builtin_amdgcn_global_load_lds(Pk + (size_t)(mbase + row) * 512,
                                             &SA[buf][(i * 256 + wave * 64) * 8], 16, 0, 0);
            __builtin_amdgcn_global_load_lds(Zk + (size_t)(n0 + row) * KTOT,
                                             &SB[buf][(i * 256 + wave * 64) * 8], 16, 0, 0);
        }
    };

    // one pipeline phase. wsel: 0 -> vmcnt(8), 1 -> vmcnt(4), 2 -> vmcnt(0).
    auto phase = [&](int kt, int wsel) {
        if (wsel == 0)      asm volatile("s_waitcnt vmcnt(8)" ::: "memory");
        else if (wsel == 1) asm volatile("s_waitcnt vmcnt(4)" ::: "memory");
        else                asm volatile("s_waitcnt vmcnt(0)" ::: "memory");
        __builtin_amdgcn_sched_barrier(0);
        __builtin_amdgcn_s_barrier();          // all waves: kt data resident
        __builtin_amdgcn_sched_barrier(0);
        int buf = kt % 3;
        bf16x8 af[4], bfr[4];
        #pragma unroll
        for (int mt = 0; mt < 4; ++mt) {
            int m = wm * 64 + mt * 16 + lr;
            af[mt] = *(const bf16x8*)&SA[buf][m * 32 + lg * 8];
        }
        #pragma unroll
        for (int nt = 0; nt < 4; ++nt) {
            int n = wn * 64 + nt * 16 + lr;
            bfr[nt] = *(const bf16x8*)&SB[buf][n * 32 + lg * 8];
        }
        __builtin_amdgcn_s_setprio(1);
        #pragma unroll
        for (int mt = 0; mt < 4; ++mt)
            #pragma unroll
            for (int nt = 0; nt < 4; ++nt)
                acc[mt][nt] = __builtin_amdgcn_mfma_f32_16x16x32_bf16(af[mt], bfr[nt], acc[mt][nt], 0, 0, 0);
        __builtin_amdgcn_s_setprio(0);
        __builtin_amdgcn_sched_barrier(0);
        __builtin_amdgcn_s_barrier();          // all waves done reading buf
        __builtin_amdgcn_sched_barrier(0);
        if (kt + 3 < 160) stage(kt + 3, (kt + 3) % 3);
    };

    // prologue: fill the 3-deep ring (12 loads/wave outstanding)
    stage(0, 0);
    __builtin_amdgcn_sched_barrier(0);
    stage(1, 1);
    __builtin_amdgcn_sched_barrier(0);
    stage(2, 2);
    __builtin_amdgcn_sched_barrier(0);

    #pragma unroll 1
    for (int kt = 0; kt < 158; ++kt) phase(kt, 0);
    phase(158, 1);
    phase(159, 2);

    // ---- epilogue: residual + bias + relu ----
    #pragma unroll
    for (int mt = 0; mt < 4; ++mt)
        #pragma unroll
        for (int nt = 0; nt < 4; ++nt)
            #pragma unroll
            for (int r = 0; r < 4; ++r) {
                int m = mbase + wm * 64 + mt * 16 + lg * 4 + r;   // w
                int nf = n0 + wn * 64 + nt * 16 + lr;
                int btl = nf >> 6, o = nf & 63;
                int bt = slab0 + btl;
                int bb = bt / 12, t = bt - bb * 12;
                size_t oi = (((size_t)bb * 512 + m) * 12 + t) * 64 + o;
                float v = acc[mt][nt][r] + x[oi] + bias[o];
                out[oi] = (v > 0.f) ? v : 0.f;
            }
}

// ---------------------------------------------------------------------------
// Fallback fused kernel (R9 structure, f32 x path) — used only if ws is tiny.
// ---------------------------------------------------------------------------
__global__ __launch_bounds__(256, 2) void k_main_fb(const float* __restrict__ x,
                                                    const ushortT* __restrict__ P,
                                                    const ushortT* __restrict__ Wq,
                                                    const float* __restrict__ bias,
                                                    float* __restrict__ out) {
    __shared__ ushortT Zt[64 * ZLD];
    const int SZ = 512 * 512;
    int bid = blockIdx.x;
    int slot = bid & 7, idx = bid >> 3;
    int half = slot >> 2;
    int bt = idx * 4 + (slot & 3);
    int b = bt / 12, tt = bt - b * 12;
    int tid = threadIdx.x, wave = tid >> 6, lane = tid & 63;
    int lr = lane & 15, lg = lane >> 4;
    int wbase = half * 256 + wave * 64;
    int vzb = wave * 64;
    const float* xqf = x + ((size_t)b * 512 * 12 + tt) * 64;

    f32x4 oacc[4][4] = {};
    bf16x8 xn[4][2];

    auto xload = [&](int ch) {
        #pragma unroll
        for (int vt = 0; vt < 4; ++vt) {
            int vrow = ch * 256 + vzb + vt * 16 + lr;
            const float* px = xqf + (size_t)vrow * 768 + lg * 8;
            f32x4 f0 = *(const f32x4*)px;
            f32x4 f1 = *(const f32x4*)(px + 4);
            f32x4 f2 = *(const f32x4*)(px + 32);
            f32x4 f3 = *(const f32x4*)(px + 36);
            bf16x8 v0, v1;
            v0[0] = (short)f2bf(f0[0]); v0[1] = (short)f2bf(f0[1]);
            v0[2] = (short)f2bf(f0[2]); v0[3] = (short)f2bf(f0[3]);
            v0[4] = (short)f2bf(f1[0]); v0[5] = (short)f2bf(f1[1]);
            v0[6] = (short)f2bf(f1[2]); v0[7] = (short)f2bf(f1[3]);
            v1[0] = (short)f2bf(f2[0]); v1[1] = (short)f2bf(f2[1]);
            v1[2] = (short)f2bf(f2[2]); v1[3] = (short)f2bf(f2[3]);
            v1[4] = (short)f2bf(f3[0]); v1[5] = (short)f2bf(f3[1]);
            v1[6] = (short)f2bf(f3[2]); v1[7] = (short)f2bf(f3[3]);
            xn[vt][0] = v0;
            xn[vt][1] = v1;
        }
    };
    auto zphase = [&](int q) {
        const ushortT* wqp = Wq + q * 4096;
        #pragma unroll
        for (int vt = 0; vt < 4; ++vt)
            #pragma unroll
            for (int ot = 0; ot < 4; ++ot) {
                int o = ot * 16 + lr;
                bf16x8 wf0 = *(const bf16x8*)(wqp + o * 64 + lg * 8);
                bf16x8 wf1 = *(const bf16x8*)(wqp + o * 64 + 32 + lg * 8);
                f32x4 z = {};
                z = __builtin_amdgcn_mfma_f32_16x16x32_bf16(xn[vt][0], wf0, z, 0, 0, 0);
                z = __builtin_amdgcn_mfma_f32_16x16x32_bf16(xn[vt][1], wf1, z, 0, 0, 0);
                us4 pk = { f2bf(z[0]), f2bf(z[1]), f2bf(z[2]), f2bf(z[3]) };
                *(us4*)&Zt[o * ZLD + vzb + vt * 16 + lg * 4] = pk;
            }
    };
    auto pptr = [&](int j, int mt) -> const ushortT* {
        int q = 1 + (j >> 1), ch = j & 1;
        return P + (size_t)q * SZ + (size_t)(wbase + mt * 16 + lr) * 512 + ch * 256 + lg * 8;
    };

    xload(half);
    zphase(0);
    xload(0);
    __syncthreads();
    #pragma unroll
    for (int mt = 0; mt < 4; ++mt)
        #pragma unroll
        for (int ot = 0; ot < 4; ++ot) {
            int o = ot * 16 + lr;
            us4 z4 = *(const us4*)&Zt[o * ZLD + wave * 64 + mt * 16 + lg * 4];
            oacc[mt][ot][0] = bf2f(z4[0]);
            oacc[mt][ot][1] = bf2f(z4[1]);
            oacc[mt][ot][2] = bf2f(z4[2]);
            oacc[mt][ot][3] = bf2f(z4[3]);
        }
    __syncthreads();

    #pragma unroll 1
    for (int j = 0; j < 18; ++j) {
        int q = 1 + (j >> 1);
        zphase(q);
        int jn = (j < 17) ? j + 1 : 17;
        xload(jn & 1);
        __syncthreads();
        const ushortT* pc0 = pptr(j, 0);
        const ushortT* pc1 = pptr(j, 1);
        const ushortT* pc2 = pptr(j, 2);
        const ushortT* pc3 = pptr(j, 3);
        #pragma unroll
        for (int kk = 0; kk < 8; ++kk) {
            bf16x8 a0 = *(const bf16x8*)(pc0 + kk * 32);
            bf16x8 a1 = *(const bf16x8*)(pc1 + kk * 32);
            bf16x8 a2 = *(const bf16x8*)(pc2 + kk * 32);
            bf16x8 a3 = *(const bf16x8*)(pc3 + kk * 32);
            int vb = kk * 32 + lg * 8;
            bf16x8 b0 = *(const bf16x8*)&Zt[(0 * 16 + lr) * ZLD + vb];
            bf16x8 b1 = *(const bf16x8*)&Zt[(1 * 16 + lr) * ZLD + vb];
            bf16x8 b2 = *(const bf16x8*)&Zt[(2 * 16 + lr) * ZLD + vb];
            bf16x8 b3 = *(const bf16x8*)&Zt[(3 * 16 + lr) * ZLD + vb];
            oacc[0][0] = __builtin_amdgcn_mfma_f32_16x16x32_bf16(a0, b0, oacc[0][0], 0, 0, 0);
            oacc[1][0] = __builtin_amdgcn_mfma_f32_16x16x32_bf16(a1, b0, oacc[1][0], 0, 0, 0);
            oacc[2][0] = __builtin_amdgcn_mfma_f32_16x16x32_bf16(a2, b0, oacc[2][0], 0, 0, 0);
            oacc[3][0] = __builtin_amdgcn_mfma_f32_16x16x32_bf16(a3, b0, oacc[3][0], 0, 0, 0);
            oacc[0][1] = __builtin_amdgcn_mfma_f32_16x16x32_bf16(a0, b1, oacc[0][1], 0, 0, 0);
            oacc[1][1] = __builtin_amdgcn_mfma_f32_16x16x32_bf16(a1, b1, oacc[1][1], 0, 0, 0);
            oacc[2][1] = __builtin_amdgcn_mfma_f32_16x16x32_bf16(a2, b1, oacc[2][1], 0, 0, 0);
            oacc[3][1] = __builtin_amdgcn_mfma_f32_16x16x32_bf16(a3, b1, oacc[3][1], 0, 0, 0);
            oacc[0][2] = __builtin_amdgcn_mfma_f32_16x16x32_bf16(a0, b2, oacc[0][2], 0, 0, 0);
            oacc[1][2] = __builtin_amdgcn_mfma_f32_16x16x32_bf16(a1, b2, oacc[1][2], 0, 0, 0);
            oacc[2][2] = __builtin_amdgcn_mfma_f32_16x16x32_bf16(a2, b2, oacc[2][2], 0, 0, 0);
            oacc[3][2] = __builtin_amdgcn_mfma_f32_16x16x32_bf16(a3, b2, oacc[3][2], 0, 0, 0);
            oacc[0][3] = __builtin_amdgcn_mfma_f32_16x16x32_bf16(a0, b3, oacc[0][3], 0, 0, 0);
            oacc[1][3] = __builtin_amdgcn_mfma_f32_16x16x32_bf16(a1, b3, oacc[1][3], 0, 0, 0);
            oacc[2][3] = __builtin_amdgcn_mfma_f32_16x16x32_bf16(a2, b3, oacc[2][3], 0, 0, 0);
            oacc[3][3] = __builtin_amdgcn_mfma_f32_16x16x32_bf16(a3, b3, oacc[3][3], 0, 0, 0);
        }
        __syncthreads();
    }

    #pragma unroll
    for (int mt = 0; mt < 4; ++mt)
        #pragma unroll
        for (int ot = 0; ot < 4; ++ot)
            #pragma unroll
            for (int r = 0; r < 4; ++r) {
                int w = wbase + mt * 16 + lg * 4 + r;
                int o = ot * 16 + lr;
                size_t oi = (((size_t)b * 512 + w) * 12 + tt) * 64 + o;
                float v = oacc[mt][ot][r] + x[oi] + bias[o];
                out[oi] = (v > 0.f) ? v : 0.f;
            }
}

// ---------------------------------------------------------------------------
extern "C" void kernel_launch(void* const* d_in, const int* in_sizes, int n_in,
                              void* d_out, int out_size, void* d_ws, size_t ws_size,
                              hipStream_t stream) {
    const float* x    = (const float*)d_in[0];
    const float* adj  = (const float*)d_in[1];
    const float* emb  = (const float*)d_in[2];
    const float* W1   = (const float*)d_in[3];
    const float* W2   = (const float*)d_in[4];
    const float* mlpw = (const float*)d_in[5];
    const float* mlpb = (const float*)d_in[6];
    float* out = (float*)d_out;

    char* ws = (char*)d_ws;
    float*   e1   = (float*)(ws + 0);
    float*   e2   = (float*)(ws + 65536);
    float*   A    = (float*)(ws + 131072);
    float*   dvec = (float*)(ws + 1179648);
    ushortT* P    = (ushortT*)(ws + 1183744);   // [10][512][512] bf16 (slot0 = I)
    ushortT* Wq   = (ushortT*)(ws + 6426624);   // [10][64][64]  bf16
    ushortT* Z    = (ushortT*)(ws + 6508544);   // B' slab buffer
    const size_t ZOFF = 6508544;

    k_embed<<<2, 256, 0, stream>>>(emb, W1, W2, e1, e2);
    k_adj<<<512, 256, 0, stream>>>(adj, e1, e2, A, dvec);
    k_m<<<512, 256, 0, stream>>>(A, dvec, P);
    k_w<<<160, 256, 0, stream>>>(mlpw, Wq);

    const int SZ = 512 * 512;
    ushortT *S1 = P + 1 * SZ, *S2 = P + 2 * SZ, *S3 = P + 3 * SZ, *S4 = P + 4 * SZ,
            *S5 = P + 5 * SZ, *S6 = P + 6 * SZ, *S7 = P + 7 * SZ, *S8 = P + 8 * SZ,
            *S9 = P + 9 * SZ;
    // S2 = M^2 ; S4 = 2M^2 - I (T2^T)
    k_gemm512<<<64, 256, 0, stream>>>(S1, S1, S2, S4, 1, nullptr, nullptr, nullptr, nullptr);
    // S3 = M^3 ; S7 = 4M^3 - 3M (T3^T)  ||  S5 = (T2^T)^2
    k_gemm512<<<128, 256, 0, stream>>>(S1, S2, S3, S7, 2, S1, S4, S4, S5);
    // S6 = (T2^T)^3  ||  S8 = (T3^T)^2
    k_gemm512<<<128, 256, 0, stream>>>(S4, S5, S6, nullptr, 0, nullptr, S7, S7, S8);
    // S9 = (T3^T)^3
    k_gemm512<<<64, 256, 0, stream>>>(S7, S8, S9, nullptr, 0, nullptr, nullptr, nullptr, nullptr);

    const size_t ZFULL = (size_t)24576 * KTOT * 2;   // 251.7 MB
    int nslab = 1;
    while (nslab <= 8 && ws_size < ZOFF + ZFULL / (size_t)nslab) nslab <<= 1;

    if (nslab <= 8) {
        int btps = 384 / nslab;
        for (int s = 0; s < nslab; ++s) {
            k_z<<<btps * 2, 256, 0, stream>>>(x, Wq, Z, s * btps);
            k_big<<<btps * 2, 256, 0, stream>>>(P, Z, x, mlpb, out, s * btps);
        }
    } else {
        k_main_fb<<<768, 256, 0, stream>>>(x, P, Wq, mlpb, out);
    }
    (void)in_sizes; (void)n_in; (void)out_size;
}